// Round 1
// baseline (1213.961 us; speedup 1.0000x reference)
//
#include <hip/hip_runtime.h>
#include <hip/hip_bf16.h>
#include <math.h>

// MambaBlock fused pipeline, fp32 v1 (correctness-first).
// ws layout (floats): xn[6291456] | xln1[6291456] | abc[6291456] | y[2097152]
//                     | xr[6291456] | sums[32768] | carries[16384]
// total 27,312,128 floats = 109,248,512 B. sout aliases xn; bf16 hidden aliases xln1+abc.

#define DEV static __device__ __forceinline__

constexpr int Bn = 8, Dm = 192, Ln = 4096, Sn = 64, Hd = 768;

DEV float wave_sum(float v) {
#pragma unroll
  for (int off = 1; off < 64; off <<= 1) v += __shfl_xor(v, off);
  return v;
}

DEV void fma4(float* acc, float ys, float4 w4) {
  acc[0] += ys * w4.x; acc[1] += ys * w4.y; acc[2] += ys * w4.z; acc[3] += ys * w4.w;
}

// ---- K1: transpose + ln1 + ssm_ln ------------------------------------------
__global__ __launch_bounds__(256) void k_ln(
    const float* __restrict__ x, const float* __restrict__ g1, const float* __restrict__ b1,
    const float* __restrict__ g2, const float* __restrict__ b2,
    float* __restrict__ xn, float* __restrict__ xln1) {
  __shared__ __align__(16) float tile[Dm * 65];
  int b = blockIdx.y, l0 = blockIdx.x * 64, tid = threadIdx.x;
  const float* xb = x + (size_t)b * Dm * Ln;
  for (int i = tid; i < Dm * 16; i += 256) {
    int d = i >> 4, l4 = (i & 15) << 2;
    float4 v = *(const float4*)&xb[d * Ln + l0 + l4];
    tile[d * 65 + l4]     = v.x; tile[d * 65 + l4 + 1] = v.y;
    tile[d * 65 + l4 + 2] = v.z; tile[d * 65 + l4 + 3] = v.w;
  }
  __syncthreads();
  int lane = tid & 63, wv = tid >> 6;
  float ga0 = g1[lane], ga1 = g1[lane + 64], ga2 = g1[lane + 128];
  float bb0 = b1[lane], bb1 = b1[lane + 64], bb2 = b1[lane + 128];
  float gc0 = g2[lane], gc1 = g2[lane + 64], gc2 = g2[lane + 128];
  float bc0 = b2[lane], bc1 = b2[lane + 64], bc2 = b2[lane + 128];
  for (int li = wv; li < 64; li += 4) {
    float v0 = tile[lane * 65 + li], v1 = tile[(lane + 64) * 65 + li], v2 = tile[(lane + 128) * 65 + li];
    float s  = wave_sum(v0 + v1 + v2);
    float sq = wave_sum(v0 * v0 + v1 * v1 + v2 * v2);
    float m = s * (1.f / 192.f);
    float inv = rsqrtf(sq * (1.f / 192.f) - m * m + 1e-5f);
    float y0 = (v0 - m) * inv * ga0 + bb0;
    float y1 = (v1 - m) * inv * ga1 + bb1;
    float y2 = (v2 - m) * inv * ga2 + bb2;
    float s2  = wave_sum(y0 + y1 + y2);
    float sq2 = wave_sum(y0 * y0 + y1 * y1 + y2 * y2);
    float m2 = s2 * (1.f / 192.f);
    float inv2 = rsqrtf(sq2 * (1.f / 192.f) - m2 * m2 + 1e-5f);
    size_t base = ((size_t)b * Ln + l0 + li) * Dm;
    xln1[base + lane]       = y0;
    xln1[base + lane + 64]  = y1;
    xln1[base + lane + 128] = y2;
    xn[base + lane]       = (y0 - m2) * inv2 * gc0 + bc0;
    xn[base + lane + 64]  = (y1 - m2) * inv2 * gc1 + bc1;
    xn[base + lane + 128] = (y2 - m2) * inv2 * gc2 + bc2;
  }
}

// ---- K2: 4-way projection GEMM + SSM elementwise epilogue ------------------
__global__ __launch_bounds__(256) void k_proj(
    const float* __restrict__ xn,
    const float* __restrict__ dt_w, const float* __restrict__ dt_b,
    const float* __restrict__ B_w, const float* __restrict__ C_w,
    const float* __restrict__ xp_w, const float* __restrict__ xp_b,
    const float* __restrict__ A_log, float* __restrict__ abc) {
  __shared__ __align__(16) float xnl[32 * 192];
  __shared__ float P[32 * 257];
  int r0 = blockIdx.x * 32, tid = threadIdx.x;
  const float4* xsrc = (const float4*)(xn + (size_t)r0 * 192);
  float4* xd = (float4*)xnl;
  for (int i = tid; i < 32 * 48; i += 256) xd[i] = xsrc[i];
  const float* wrow = (tid < 64)  ? dt_w + tid * 192
                    : (tid < 128) ? B_w + (tid - 64) * 192
                    : (tid < 192) ? C_w + (tid - 128) * 192
                                  : xp_w + (tid - 192) * 192;
  float acc[32];
#pragma unroll
  for (int r = 0; r < 32; r++) acc[r] = 0.f;
  __syncthreads();
  for (int k0 = 0; k0 < 192; k0 += 16) {
    float4 w0 = *(const float4*)(wrow + k0);
    float4 w1 = *(const float4*)(wrow + k0 + 4);
    float4 w2 = *(const float4*)(wrow + k0 + 8);
    float4 w3 = *(const float4*)(wrow + k0 + 12);
#pragma unroll
    for (int r = 0; r < 32; r++) {
      const float4* xp4 = (const float4*)&xnl[r * 192 + k0];
      float4 x0 = xp4[0], x1 = xp4[1], x2 = xp4[2], x3 = xp4[3];
      acc[r] += x0.x * w0.x + x0.y * w0.y + x0.z * w0.z + x0.w * w0.w
              + x1.x * w1.x + x1.y * w1.y + x1.z * w1.z + x1.w * w1.w
              + x2.x * w2.x + x2.y * w2.y + x2.z * w2.z + x2.w * w2.w
              + x3.x * w3.x + x3.y * w3.y + x3.z * w3.z + x3.w * w3.w;
    }
  }
  __syncthreads();
#pragma unroll
  for (int r = 0; r < 32; r++) P[r * 257 + tid] = acc[r];
  __syncthreads();
  int s = tid & 63, q = tid >> 6;
  float A = -expf(A_log[s]);
  float dtb = dt_b[s], xpb = xp_b[s];
  for (int r = q; r < 32; r += 4) {
    float z = P[r * 257 + s] + dtb;
    float sp = (z > 20.f) ? z : log1pf(expf(z));
    float delta = sp * 0.01f + 0.0001f;
    float bt = P[r * 257 + 64 + s];
    float ct = P[r * 257 + 128 + s];
    float xpv = P[r * 257 + 192 + s] + xpb;
    float dA = delta * A;
    dA = fminf(fmaxf(dA, -10.f), -0.0001f);
    float Ae = expf(dA);
    Ae = fminf(fmaxf(Ae, 0.001f), 0.999f) + 1e-10f;
    size_t ob = ((size_t)(r0 + r)) * 192;
    abc[ob + s]       = Ae;
    abc[ob + 64 + s]  = delta * bt * xpv;
    abc[ob + 128 + s] = ct;
  }
}

// ---- K3: scan phase 1 (per-chunk summaries) --------------------------------
__global__ __launch_bounds__(64) void k_scan1(const float* __restrict__ abc, float* __restrict__ sums) {
  int c = blockIdx.x, b = blockIdx.y, s = threadIdx.x;
  const float* p = abc + ((size_t)b * Ln + c * 128) * 192;
  float prodA = 1.f, h = 0.f;
  int t = 0;
  if (c == 0) { prodA = p[s]; h = p[64 + s]; t = 1; }
#pragma unroll 4
  for (; t < 128; t++) {
    float a = p[t * 192 + s], bx = p[t * 192 + 64 + s];
    h = a * (h + bx);
    prodA *= a;
  }
  sums[(((b * 32 + c) * 2 + 0) << 6) + s] = prodA;
  sums[(((b * 32 + c) * 2 + 1) << 6) + s] = h;
}

// ---- K4: scan phase 2 (carry chain over 32 chunks) -------------------------
__global__ __launch_bounds__(512) void k_scan2(const float* __restrict__ sums, float* __restrict__ carries) {
  int tid = threadIdx.x, b = tid >> 6, s = tid & 63;
  float cur = 0.f;
  for (int c = 0; c < 32; c++) {
    carries[((b * 32 + c) << 6) + s] = cur;
    float a  = sums[(((b * 32 + c) * 2 + 0) << 6) + s];
    float bb = sums[(((b * 32 + c) * 2 + 1) << 6) + s];
    cur = a * cur + bb;
  }
}

// ---- K5: scan phase 3 (replay with carries, y = C*h) -----------------------
__global__ __launch_bounds__(64) void k_scan3(const float* __restrict__ abc, const float* __restrict__ carries,
                                              float* __restrict__ y) {
  int c = blockIdx.x, b = blockIdx.y, s = threadIdx.x;
  size_t r0 = (size_t)b * Ln + c * 128;
  const float* p = abc + r0 * 192;
  float* yo = y + r0 * 64;
  float h = carries[((b * 32 + c) << 6) + s];
  int t = 0;
  if (c == 0) { h = p[64 + s]; yo[s] = p[128 + s] * h; t = 1; }
#pragma unroll 4
  for (; t < 128; t++) {
    float a = p[t * 192 + s], bx = p[t * 192 + 64 + s], ct = p[t * 192 + 128 + s];
    h = a * (h + bx);
    yo[t * 64 + s] = ct * h;
  }
}

// ---- K6: SSM out-projection (+D skip), transpose-write to NCHW -------------
__global__ __launch_bounds__(256) void k_out(
    const float* __restrict__ y, const float* __restrict__ out_w, const float* __restrict__ out_b,
    const float* __restrict__ Dp, const float* __restrict__ xln1, float* __restrict__ sout) {
  __shared__ __align__(16) float yl[32 * 68];
  __shared__ __align__(16) float owl[64 * 196];  // [s][d]
  int b = blockIdx.y, l0 = blockIdx.x * 32, tid = threadIdx.x;
  for (int i = tid; i < 32 * 64; i += 256) {
    int l = i >> 6, s = i & 63;
    yl[l * 68 + s] = y[((size_t)b * Ln + l0 + l) * 64 + s];
  }
  for (int i = tid; i < 64 * 192; i += 256) {
    int d = i >> 6, s = i & 63;
    owl[s * 196 + d] = out_w[i];
  }
  __syncthreads();
  int lg = tid & 15, dg = tid >> 4;  // l = lg + 16*rl (rl 0..1), d = dg*12 + j
  float acc[2][12];
#pragma unroll
  for (int j = 0; j < 12; j++) { acc[0][j] = 0.f; acc[1][j] = 0.f; }
#pragma unroll 4
  for (int s = 0; s < 64; s += 4) {
    float4 y0 = *(const float4*)&yl[lg * 68 + s];
    float4 y1 = *(const float4*)&yl[(lg + 16) * 68 + s];
    float ys0[4] = {y0.x, y0.y, y0.z, y0.w};
    float ys1[4] = {y1.x, y1.y, y1.z, y1.w};
#pragma unroll
    for (int ss = 0; ss < 4; ss++) {
#pragma unroll
      for (int j = 0; j < 3; j++) {
        float4 w4 = *(const float4*)&owl[(s + ss) * 196 + dg * 12 + j * 4];
        fma4(&acc[0][j * 4], ys0[ss], w4);
        fma4(&acc[1][j * 4], ys1[ss], w4);
      }
    }
  }
#pragma unroll
  for (int j = 0; j < 12; j++) {
    int d = dg * 12 + j;
    float ob = out_b[d];
    float dc = fminf(fmaxf(Dp[d], -2.f), 2.f);
#pragma unroll
    for (int rl = 0; rl < 2; rl++) {
      int l = lg + 16 * rl;
      float v = acc[rl][j] + ob;
      if (dc != 0.f) v += dc * xln1[((size_t)b * Ln + l0 + l) * 192 + d];
      sout[((size_t)b * Dm + d) * Ln + l0 + l] = v;
    }
  }
}

// ---- K7: depthwise conv 3x3 + BN + residual combine -> xr (NCHW) -----------
__global__ __launch_bounds__(256) void k_conv(
    const float* __restrict__ x, const float* __restrict__ dw,
    const float* __restrict__ bn_g, const float* __restrict__ bn_b,
    const float* __restrict__ bn_rm, const float* __restrict__ bn_rv,
    const float* __restrict__ sout, const float* __restrict__ a_loc,
    const float* __restrict__ a_ssm, float* __restrict__ xr) {
  __shared__ __align__(16) float xs[64 * 64];
  int d = blockIdx.x, b = blockIdx.y, tid = threadIdx.x;
  const float* xp = x + ((size_t)b * Dm + d) * Ln;
  for (int i = tid; i < 1024; i += 256) ((float4*)xs)[i] = ((const float4*)xp)[i];
  __syncthreads();
  float w[9];
#pragma unroll
  for (int k = 0; k < 9; k++) w[k] = dw[d * 9 + k];
  float scale = bn_g[d] * rsqrtf(bn_rv[d] + 1e-5f);
  float rm = bn_rm[d], bb = bn_b[d];
  float al = a_loc[0], as_ = a_ssm[0];
  const float* sp = sout + ((size_t)b * Dm + d) * Ln;
  float* xo = xr + ((size_t)b * Dm + d) * Ln;
  for (int i = tid; i < 4096; i += 256) {
    int h = i >> 6, wc = i & 63;
    float acc = 0.f;
#pragma unroll
    for (int kh = 0; kh < 3; kh++) {
      int hh = h + kh - 1;
      if (hh < 0 || hh >= 64) continue;
#pragma unroll
      for (int kw = 0; kw < 3; kw++) {
        int ww2 = wc + kw - 1;
        if (ww2 < 0 || ww2 >= 64) continue;
        acc += xs[hh * 64 + ww2] * w[kh * 3 + kw];
      }
    }
    float xl = (acc - rm) * scale + bb;
    xo[i] = xs[i] + al * xl + as_ * sp[i];
  }
}

// ---- K8: ln2 + MLP fc1 + exact GELU -> bf16 hidden -------------------------
__global__ __launch_bounds__(256) void k_mlp1(
    const float* __restrict__ xr, const float* __restrict__ g2, const float* __restrict__ b2,
    const float* __restrict__ w1, const float* __restrict__ b1h,
    __hip_bfloat16* __restrict__ hid) {
  __shared__ __align__(16) float tile[Dm * 33];   // also reused as W chunk
  __shared__ __align__(16) float xn2[32 * 196];
  int lt = blockIdx.x, cb = blockIdx.y, b = blockIdx.z, tid = threadIdx.x;
  int l0 = lt * 32;
  const float* xb = xr + (size_t)b * Dm * Ln;
  for (int i = tid; i < Dm * 8; i += 256) {
    int d = i >> 3, l4 = (i & 7) << 2;
    float4 v = *(const float4*)&xb[d * Ln + l0 + l4];
    tile[d * 33 + l4]     = v.x; tile[d * 33 + l4 + 1] = v.y;
    tile[d * 33 + l4 + 2] = v.z; tile[d * 33 + l4 + 3] = v.w;
  }
  __syncthreads();
  int lane = tid & 63, wv = tid >> 6;
  for (int li = wv; li < 32; li += 4) {
    float v0 = tile[lane * 33 + li], v1 = tile[(lane + 64) * 33 + li], v2 = tile[(lane + 128) * 33 + li];
    float s  = wave_sum(v0 + v1 + v2);
    float sq = wave_sum(v0 * v0 + v1 * v1 + v2 * v2);
    float m = s * (1.f / 192.f);
    float inv = rsqrtf(sq * (1.f / 192.f) - m * m + 1e-5f);
    xn2[li * 196 + lane]       = (v0 - m) * inv * g2[lane] + b2[lane];
    xn2[li * 196 + lane + 64]  = (v1 - m) * inv * g2[lane + 64] + b2[lane + 64];
    xn2[li * 196 + lane + 128] = (v2 - m) * inv * g2[lane + 128] + b2[lane + 128];
  }
  float* Wl = tile;  // [192 cc][12 kk]
  int lg = tid & 15, cg = tid >> 4;  // l = lg + 16*rl, c = cg*12 + j
  float acc[2][12];
#pragma unroll
  for (int j = 0; j < 12; j++) { acc[0][j] = 0.f; acc[1][j] = 0.f; }
  for (int k0 = 0; k0 < 192; k0 += 12) {
    __syncthreads();
    for (int i = tid; i < 192 * 3; i += 256) {
      int cc = i / 3, qq = i - cc * 3;
      *(float4*)&Wl[cc * 12 + qq * 4] =
          *(const float4*)&w1[((size_t)(cb * 192 + cc)) * 192 + k0 + qq * 4];
    }
    __syncthreads();
#pragma unroll
    for (int kk = 0; kk < 12; kk += 4) {
      float4 x0 = *(const float4*)&xn2[lg * 196 + k0 + kk];
      float4 x1 = *(const float4*)&xn2[(lg + 16) * 196 + k0 + kk];
#pragma unroll
      for (int j = 0; j < 12; j++) {
        float4 w4 = *(const float4*)&Wl[(cg * 12 + j) * 12 + kk];
        acc[0][j] += x0.x * w4.x + x0.y * w4.y + x0.z * w4.z + x0.w * w4.w;
        acc[1][j] += x1.x * w4.x + x1.y * w4.y + x1.z * w4.z + x1.w * w4.w;
      }
    }
  }
#pragma unroll
  for (int j = 0; j < 12; j++) {
    int c = cg * 12 + j;
    float bias = b1h[cb * 192 + c];
#pragma unroll
    for (int rl = 0; rl < 2; rl++) {
      float v = acc[rl][j] + bias;
      float g = 0.5f * v * (1.f + erff(v * 0.70710678118f));
      int l = lg + 16 * rl;
      hid[((size_t)b * Ln + l0 + l) * Hd + cb * 192 + c] = __float2bfloat16(g);
    }
  }
}

// ---- K9: MLP fc2 + final residual, transpose-write NCHW --------------------
__global__ __launch_bounds__(256) void k_mlp2(
    const __hip_bfloat16* __restrict__ hid, const float* __restrict__ w2,
    const float* __restrict__ b2o, const float* __restrict__ xr,
    const float* __restrict__ am, float* __restrict__ out) {
  __shared__ __align__(16) float hl[64 * 36];
  __shared__ __align__(16) float Wl[192 * 36];
  int b = blockIdx.y, l0 = blockIdx.x * 64, tid = threadIdx.x;
  int lg = tid & 15, dg = tid >> 4;  // l = lg + 16*rl (rl 0..3), d = dg*12 + j
  float acc[4][12];
#pragma unroll
  for (int rl = 0; rl < 4; rl++)
#pragma unroll
    for (int j = 0; j < 12; j++) acc[rl][j] = 0.f;
  for (int k0 = 0; k0 < 768; k0 += 32) {
    __syncthreads();
    for (int i = tid; i < 64 * 32; i += 256) {
      int l = i >> 5, kk = i & 31;
      hl[l * 36 + kk] = __bfloat162float(hid[((size_t)b * Ln + l0 + l) * Hd + k0 + kk]);
    }
    for (int i = tid; i < 192 * 8; i += 256) {
      int d = i >> 3, qq = i & 7;
      *(float4*)&Wl[d * 36 + qq * 4] = *(const float4*)&w2[(size_t)d * 768 + k0 + qq * 4];
    }
    __syncthreads();
#pragma unroll
    for (int kk = 0; kk < 32; kk += 4) {
      float4 x0 = *(const float4*)&hl[lg * 36 + kk];
      float4 x1 = *(const float4*)&hl[(lg + 16) * 36 + kk];
      float4 x2 = *(const float4*)&hl[(lg + 32) * 36 + kk];
      float4 x3 = *(const float4*)&hl[(lg + 48) * 36 + kk];
#pragma unroll
      for (int j = 0; j < 12; j++) {
        float4 w4 = *(const float4*)&Wl[(dg * 12 + j) * 36 + kk];
        acc[0][j] += x0.x * w4.x + x0.y * w4.y + x0.z * w4.z + x0.w * w4.w;
        acc[1][j] += x1.x * w4.x + x1.y * w4.y + x1.z * w4.z + x1.w * w4.w;
        acc[2][j] += x2.x * w4.x + x2.y * w4.y + x2.z * w4.z + x2.w * w4.w;
        acc[3][j] += x3.x * w4.x + x3.y * w4.y + x3.z * w4.z + x3.w * w4.w;
      }
    }
  }
  float alpha = am[0];
#pragma unroll
  for (int j = 0; j < 12; j++) {
    int d = dg * 12 + j;
    float bias = b2o[d];
#pragma unroll
    for (int rl = 0; rl < 4; rl++) {
      int l = lg + 16 * rl;
      size_t idx = ((size_t)b * Dm + d) * Ln + l0 + l;
      out[idx] = xr[idx] + alpha * (acc[rl][j] + bias);
    }
  }
}

extern "C" void kernel_launch(void* const* d_in, const int* in_sizes, int n_in,
                              void* d_out, int out_size, void* d_ws, size_t ws_size,
                              hipStream_t stream) {
  (void)in_sizes; (void)n_in; (void)out_size; (void)ws_size;
  const float* x     = (const float*)d_in[0];
  const float* ln1_g = (const float*)d_in[1];
  const float* ln1_b = (const float*)d_in[2];
  const float* ln2_g = (const float*)d_in[3];
  const float* ln2_b = (const float*)d_in[4];
  const float* dw_w  = (const float*)d_in[5];
  const float* bn_g  = (const float*)d_in[6];
  const float* bn_b  = (const float*)d_in[7];
  const float* bn_rm = (const float*)d_in[8];
  const float* bn_rv = (const float*)d_in[9];
  const float* ssm_g = (const float*)d_in[10];
  const float* ssm_b = (const float*)d_in[11];
  const float* xp_w  = (const float*)d_in[12];
  const float* xp_b  = (const float*)d_in[13];
  const float* dt_w  = (const float*)d_in[14];
  const float* dt_b  = (const float*)d_in[15];
  const float* A_log = (const float*)d_in[16];
  const float* B_w   = (const float*)d_in[17];
  const float* C_w   = (const float*)d_in[18];
  const float* Dp    = (const float*)d_in[19];
  const float* out_w = (const float*)d_in[20];
  const float* out_b = (const float*)d_in[21];
  const float* w1    = (const float*)d_in[22];
  const float* b1    = (const float*)d_in[23];
  const float* w2    = (const float*)d_in[24];
  const float* b2    = (const float*)d_in[25];
  const float* a_loc = (const float*)d_in[26];
  const float* a_ssm = (const float*)d_in[27];
  const float* a_mlp = (const float*)d_in[28];

  float* ws = (float*)d_ws;
  float* xn      = ws;
  float* xln1    = ws + 6291456;
  float* abc     = ws + 12582912;
  float* yb      = ws + 18874368;
  float* xr      = ws + 20971520;
  float* sums    = ws + 27262976;
  float* carries = ws + 27295744;
  float* sout = xn;                                    // xn dead after k_proj
  __hip_bfloat16* hid = (__hip_bfloat16*)(ws + 6291456);  // xln1+abc dead after k_out/scan
  float* out = (float*)d_out;

  k_ln   <<<dim3(64, 8),      256, 0, stream>>>(x, ln1_g, ln1_b, ssm_g, ssm_b, xn, xln1);
  k_proj <<<dim3(1024),       256, 0, stream>>>(xn, dt_w, dt_b, B_w, C_w, xp_w, xp_b, A_log, abc);
  k_scan1<<<dim3(32, 8),       64, 0, stream>>>(abc, sums);
  k_scan2<<<dim3(1),          512, 0, stream>>>(sums, carries);
  k_scan3<<<dim3(32, 8),       64, 0, stream>>>(abc, carries, yb);
  k_out  <<<dim3(128, 8),     256, 0, stream>>>(yb, out_w, out_b, Dp, xln1, sout);
  k_conv <<<dim3(192, 8),     256, 0, stream>>>(x, dw_w, bn_g, bn_b, bn_rm, bn_rv, sout, a_loc, a_ssm, xr);
  k_mlp1 <<<dim3(128, 4, 8),  256, 0, stream>>>(xr, ln2_g, ln2_b, w1, b1, hid);
  k_mlp2 <<<dim3(64, 8),      256, 0, stream>>>(hid, w2, b2, xr, a_mlp, out);
}

// Round 2
// 426.521 us; speedup vs baseline: 2.8462x; 2.8462x over previous
//
#include <hip/hip_runtime.h>
#include <hip/hip_bf16.h>
#include <math.h>

// MambaBlock fused pipeline v2: MFMA bf16 MLP.
// ws layout (floats): xn[6291456] | xln1[6291456] | abc[6291456] | yb[2097152]
//                     | xr[6291456] | sums[32768] | carries[16384]
// Aliases: sout=xn (after k_proj); xn2 bf16 = xn region (after k_conv);
//          hid bf16 = xln1+abc region (after k_conv); w1b/w2b bf16 = yb region (after k_out).

#define DEV static __device__ __forceinline__

constexpr int Bn = 8, Dm = 192, Ln = 4096, Sn = 64, Hd = 768;

typedef __attribute__((ext_vector_type(8))) short bf16x8;
typedef __attribute__((ext_vector_type(4))) float f32x4;

DEV float wave_sum(float v) {
#pragma unroll
  for (int off = 1; off < 64; off <<= 1) v += __shfl_xor(v, off);
  return v;
}

DEV void fma4(float* acc, float ys, float4 w4) {
  acc[0] += ys * w4.x; acc[1] += ys * w4.y; acc[2] += ys * w4.z; acc[3] += ys * w4.w;
}

DEV short f2b(float x) {
  __hip_bfloat16 h = __float2bfloat16(x);
  return *(short*)&h;
}

// ---- K1: transpose + ln1 + ssm_ln ------------------------------------------
__global__ __launch_bounds__(256) void k_ln(
    const float* __restrict__ x, const float* __restrict__ g1, const float* __restrict__ b1,
    const float* __restrict__ g2, const float* __restrict__ b2,
    float* __restrict__ xn, float* __restrict__ xln1) {
  __shared__ __align__(16) float tile[Dm * 65];
  int b = blockIdx.y, l0 = blockIdx.x * 64, tid = threadIdx.x;
  const float* xb = x + (size_t)b * Dm * Ln;
  for (int i = tid; i < Dm * 16; i += 256) {
    int d = i >> 4, l4 = (i & 15) << 2;
    float4 v = *(const float4*)&xb[d * Ln + l0 + l4];
    tile[d * 65 + l4]     = v.x; tile[d * 65 + l4 + 1] = v.y;
    tile[d * 65 + l4 + 2] = v.z; tile[d * 65 + l4 + 3] = v.w;
  }
  __syncthreads();
  int lane = tid & 63, wv = tid >> 6;
  float ga0 = g1[lane], ga1 = g1[lane + 64], ga2 = g1[lane + 128];
  float bb0 = b1[lane], bb1 = b1[lane + 64], bb2 = b1[lane + 128];
  float gc0 = g2[lane], gc1 = g2[lane + 64], gc2 = g2[lane + 128];
  float bc0 = b2[lane], bc1 = b2[lane + 64], bc2 = b2[lane + 128];
  for (int li = wv; li < 64; li += 4) {
    float v0 = tile[lane * 65 + li], v1 = tile[(lane + 64) * 65 + li], v2 = tile[(lane + 128) * 65 + li];
    float s  = wave_sum(v0 + v1 + v2);
    float sq = wave_sum(v0 * v0 + v1 * v1 + v2 * v2);
    float m = s * (1.f / 192.f);
    float inv = rsqrtf(sq * (1.f / 192.f) - m * m + 1e-5f);
    float y0 = (v0 - m) * inv * ga0 + bb0;
    float y1 = (v1 - m) * inv * ga1 + bb1;
    float y2 = (v2 - m) * inv * ga2 + bb2;
    float s2  = wave_sum(y0 + y1 + y2);
    float sq2 = wave_sum(y0 * y0 + y1 * y1 + y2 * y2);
    float m2 = s2 * (1.f / 192.f);
    float inv2 = rsqrtf(sq2 * (1.f / 192.f) - m2 * m2 + 1e-5f);
    size_t base = ((size_t)b * Ln + l0 + li) * Dm;
    xln1[base + lane]       = y0;
    xln1[base + lane + 64]  = y1;
    xln1[base + lane + 128] = y2;
    xn[base + lane]       = (y0 - m2) * inv2 * gc0 + bc0;
    xn[base + lane + 64]  = (y1 - m2) * inv2 * gc1 + bc1;
    xn[base + lane + 128] = (y2 - m2) * inv2 * gc2 + bc2;
  }
}

// ---- K2: 4-way projection GEMM + SSM elementwise epilogue ------------------
__global__ __launch_bounds__(256) void k_proj(
    const float* __restrict__ xn,
    const float* __restrict__ dt_w, const float* __restrict__ dt_b,
    const float* __restrict__ B_w, const float* __restrict__ C_w,
    const float* __restrict__ xp_w, const float* __restrict__ xp_b,
    const float* __restrict__ A_log, float* __restrict__ abc) {
  __shared__ __align__(16) float xnl[32 * 192];
  __shared__ float P[32 * 257];
  int r0 = blockIdx.x * 32, tid = threadIdx.x;
  const float4* xsrc = (const float4*)(xn + (size_t)r0 * 192);
  float4* xd = (float4*)xnl;
  for (int i = tid; i < 32 * 48; i += 256) xd[i] = xsrc[i];
  const float* wrow = (tid < 64)  ? dt_w + tid * 192
                    : (tid < 128) ? B_w + (tid - 64) * 192
                    : (tid < 192) ? C_w + (tid - 128) * 192
                                  : xp_w + (tid - 192) * 192;
  float acc[32];
#pragma unroll
  for (int r = 0; r < 32; r++) acc[r] = 0.f;
  __syncthreads();
  for (int k0 = 0; k0 < 192; k0 += 16) {
    float4 w0 = *(const float4*)(wrow + k0);
    float4 w1 = *(const float4*)(wrow + k0 + 4);
    float4 w2 = *(const float4*)(wrow + k0 + 8);
    float4 w3 = *(const float4*)(wrow + k0 + 12);
#pragma unroll
    for (int r = 0; r < 32; r++) {
      const float4* xp4 = (const float4*)&xnl[r * 192 + k0];
      float4 x0 = xp4[0], x1 = xp4[1], x2 = xp4[2], x3 = xp4[3];
      acc[r] += x0.x * w0.x + x0.y * w0.y + x0.z * w0.z + x0.w * w0.w
              + x1.x * w1.x + x1.y * w1.y + x1.z * w1.z + x1.w * w1.w
              + x2.x * w2.x + x2.y * w2.y + x2.z * w2.z + x2.w * w2.w
              + x3.x * w3.x + x3.y * w3.y + x3.z * w3.z + x3.w * w3.w;
    }
  }
  __syncthreads();
#pragma unroll
  for (int r = 0; r < 32; r++) P[r * 257 + tid] = acc[r];
  __syncthreads();
  int s = tid & 63, q = tid >> 6;
  float A = -expf(A_log[s]);
  float dtb = dt_b[s], xpb = xp_b[s];
  for (int r = q; r < 32; r += 4) {
    float z = P[r * 257 + s] + dtb;
    float sp = (z > 20.f) ? z : log1pf(expf(z));
    float delta = sp * 0.01f + 0.0001f;
    float bt = P[r * 257 + 64 + s];
    float ct = P[r * 257 + 128 + s];
    float xpv = P[r * 257 + 192 + s] + xpb;
    float dA = delta * A;
    dA = fminf(fmaxf(dA, -10.f), -0.0001f);
    float Ae = expf(dA);
    Ae = fminf(fmaxf(Ae, 0.001f), 0.999f) + 1e-10f;
    size_t ob = ((size_t)(r0 + r)) * 192;
    abc[ob + s]       = Ae;
    abc[ob + 64 + s]  = delta * bt * xpv;
    abc[ob + 128 + s] = ct;
  }
}

// ---- K3: scan phase 1 (per-chunk summaries) --------------------------------
__global__ __launch_bounds__(64) void k_scan1(const float* __restrict__ abc, float* __restrict__ sums) {
  int c = blockIdx.x, b = blockIdx.y, s = threadIdx.x;
  const float* p = abc + ((size_t)b * Ln + c * 128) * 192;
  float prodA = 1.f, h = 0.f;
  int t = 0;
  if (c == 0) { prodA = p[s]; h = p[64 + s]; t = 1; }
#pragma unroll 4
  for (; t < 128; t++) {
    float a = p[t * 192 + s], bx = p[t * 192 + 64 + s];
    h = a * (h + bx);
    prodA *= a;
  }
  sums[(((b * 32 + c) * 2 + 0) << 6) + s] = prodA;
  sums[(((b * 32 + c) * 2 + 1) << 6) + s] = h;
}

// ---- K4: scan phase 2 (carry chain over 32 chunks) -------------------------
__global__ __launch_bounds__(512) void k_scan2(const float* __restrict__ sums, float* __restrict__ carries) {
  int tid = threadIdx.x, b = tid >> 6, s = tid & 63;
  float cur = 0.f;
  for (int c = 0; c < 32; c++) {
    carries[((b * 32 + c) << 6) + s] = cur;
    float a  = sums[(((b * 32 + c) * 2 + 0) << 6) + s];
    float bb = sums[(((b * 32 + c) * 2 + 1) << 6) + s];
    cur = a * cur + bb;
  }
}

// ---- K5: scan phase 3 (replay with carries, y = C*h) -----------------------
__global__ __launch_bounds__(64) void k_scan3(const float* __restrict__ abc, const float* __restrict__ carries,
                                              float* __restrict__ y) {
  int c = blockIdx.x, b = blockIdx.y, s = threadIdx.x;
  size_t r0 = (size_t)b * Ln + c * 128;
  const float* p = abc + r0 * 192;
  float* yo = y + r0 * 64;
  float h = carries[((b * 32 + c) << 6) + s];
  int t = 0;
  if (c == 0) { h = p[64 + s]; yo[s] = p[128 + s] * h; t = 1; }
#pragma unroll 4
  for (; t < 128; t++) {
    float a = p[t * 192 + s], bx = p[t * 192 + 64 + s], ct = p[t * 192 + 128 + s];
    h = a * (h + bx);
    yo[t * 64 + s] = ct * h;
  }
}

// ---- K6: SSM out-projection (+D skip), transpose-write to NCHW -------------
__global__ __launch_bounds__(256) void k_out(
    const float* __restrict__ y, const float* __restrict__ out_w, const float* __restrict__ out_b,
    const float* __restrict__ Dp, const float* __restrict__ xln1, float* __restrict__ sout) {
  __shared__ __align__(16) float yl[32 * 68];
  __shared__ __align__(16) float owl[64 * 196];  // [s][d]
  int b = blockIdx.y, l0 = blockIdx.x * 32, tid = threadIdx.x;
  for (int i = tid; i < 32 * 64; i += 256) {
    int l = i >> 6, s = i & 63;
    yl[l * 68 + s] = y[((size_t)b * Ln + l0 + l) * 64 + s];
  }
  for (int i = tid; i < 64 * 192; i += 256) {
    int d = i >> 6, s = i & 63;
    owl[s * 196 + d] = out_w[i];
  }
  __syncthreads();
  int lg = tid & 15, dg = tid >> 4;  // l = lg + 16*rl (rl 0..1), d = dg*12 + j
  float acc[2][12];
#pragma unroll
  for (int j = 0; j < 12; j++) { acc[0][j] = 0.f; acc[1][j] = 0.f; }
#pragma unroll 4
  for (int s = 0; s < 64; s += 4) {
    float4 y0 = *(const float4*)&yl[lg * 68 + s];
    float4 y1 = *(const float4*)&yl[(lg + 16) * 68 + s];
    float ys0[4] = {y0.x, y0.y, y0.z, y0.w};
    float ys1[4] = {y1.x, y1.y, y1.z, y1.w};
#pragma unroll
    for (int ss = 0; ss < 4; ss++) {
#pragma unroll
      for (int j = 0; j < 3; j++) {
        float4 w4 = *(const float4*)&owl[(s + ss) * 196 + dg * 12 + j * 4];
        fma4(&acc[0][j * 4], ys0[ss], w4);
        fma4(&acc[1][j * 4], ys1[ss], w4);
      }
    }
  }
#pragma unroll
  for (int j = 0; j < 12; j++) {
    int d = dg * 12 + j;
    float ob = out_b[d];
    float dc = fminf(fmaxf(Dp[d], -2.f), 2.f);
#pragma unroll
    for (int rl = 0; rl < 2; rl++) {
      int l = lg + 16 * rl;
      float v = acc[rl][j] + ob;
      if (dc != 0.f) v += dc * xln1[((size_t)b * Ln + l0 + l) * 192 + d];
      sout[((size_t)b * Dm + d) * Ln + l0 + l] = v;
    }
  }
}

// ---- K7: depthwise conv 3x3 + BN + residual combine -> xr (NCHW) -----------
__global__ __launch_bounds__(256) void k_conv(
    const float* __restrict__ x, const float* __restrict__ dw,
    const float* __restrict__ bn_g, const float* __restrict__ bn_b,
    const float* __restrict__ bn_rm, const float* __restrict__ bn_rv,
    const float* __restrict__ sout, const float* __restrict__ a_loc,
    const float* __restrict__ a_ssm, float* __restrict__ xr) {
  __shared__ __align__(16) float xs[64 * 64];
  int d = blockIdx.x, b = blockIdx.y, tid = threadIdx.x;
  const float* xp = x + ((size_t)b * Dm + d) * Ln;
  for (int i = tid; i < 1024; i += 256) ((float4*)xs)[i] = ((const float4*)xp)[i];
  __syncthreads();
  float w[9];
#pragma unroll
  for (int k = 0; k < 9; k++) w[k] = dw[d * 9 + k];
  float scale = bn_g[d] * rsqrtf(bn_rv[d] + 1e-5f);
  float rm = bn_rm[d], bb = bn_b[d];
  float al = a_loc[0], as_ = a_ssm[0];
  const float* sp = sout + ((size_t)b * Dm + d) * Ln;
  float* xo = xr + ((size_t)b * Dm + d) * Ln;
  for (int i = tid; i < 4096; i += 256) {
    int h = i >> 6, wc = i & 63;
    float acc = 0.f;
#pragma unroll
    for (int kh = 0; kh < 3; kh++) {
      int hh = h + kh - 1;
      if (hh < 0 || hh >= 64) continue;
#pragma unroll
      for (int kw = 0; kw < 3; kw++) {
        int ww2 = wc + kw - 1;
        if (ww2 < 0 || ww2 >= 64) continue;
        acc += xs[hh * 64 + ww2] * w[kh * 3 + kw];
      }
    }
    float xl = (acc - rm) * scale + bb;
    xo[i] = xs[i] + al * xl + as_ * sp[i];
  }
}

// ---- K8: ln2 -> bf16 xn2 [B*L, 192] row-major ------------------------------
__global__ __launch_bounds__(256) void k_ln2(
    const float* __restrict__ xr, const float* __restrict__ g, const float* __restrict__ bb,
    short* __restrict__ xn2) {
  __shared__ __align__(16) float tile[Dm * 65];
  int b = blockIdx.y, l0 = blockIdx.x * 64, tid = threadIdx.x;
  const float* xb = xr + (size_t)b * Dm * Ln;
  for (int i = tid; i < Dm * 16; i += 256) {
    int d = i >> 4, l4 = (i & 15) << 2;
    float4 v = *(const float4*)&xb[d * Ln + l0 + l4];
    tile[d * 65 + l4]     = v.x; tile[d * 65 + l4 + 1] = v.y;
    tile[d * 65 + l4 + 2] = v.z; tile[d * 65 + l4 + 3] = v.w;
  }
  __syncthreads();
  int lane = tid & 63, wv = tid >> 6;
  float g0 = g[lane], g1v = g[lane + 64], g2v = g[lane + 128];
  float b0 = bb[lane], b1v = bb[lane + 64], b2v = bb[lane + 128];
  for (int li = wv; li < 64; li += 4) {
    float v0 = tile[lane * 65 + li], v1 = tile[(lane + 64) * 65 + li], v2 = tile[(lane + 128) * 65 + li];
    float s  = wave_sum(v0 + v1 + v2);
    float sq = wave_sum(v0 * v0 + v1 * v1 + v2 * v2);
    float m = s * (1.f / 192.f);
    float inv = rsqrtf(sq * (1.f / 192.f) - m * m + 1e-5f);
    size_t base = ((size_t)b * Ln + l0 + li) * Dm;
    xn2[base + lane]       = f2b((v0 - m) * inv * g0 + b0);
    xn2[base + lane + 64]  = f2b((v1 - m) * inv * g1v + b1v);
    xn2[base + lane + 128] = f2b((v2 - m) * inv * g2v + b2v);
  }
}

// ---- K9: fp32 -> bf16 weight convert (w1 then w2, flat) --------------------
__global__ __launch_bounds__(256) void k_wconv(
    const float* __restrict__ w1, const float* __restrict__ w2, short* __restrict__ dst) {
  int i = blockIdx.x * 256 + threadIdx.x;  // 73728 float4 groups
  float4 v = (i < 36864) ? ((const float4*)w1)[i] : ((const float4*)w2)[i - 36864];
  int o = i * 4;
  dst[o]     = f2b(v.x);
  dst[o + 1] = f2b(v.y);
  dst[o + 2] = f2b(v.z);
  dst[o + 3] = f2b(v.w);
}

// ---- K10: MFMA GEMM1: hid = gelu(xn2 @ w1^T + b1), bf16 out ----------------
// A = xn2 [32768,192] bf16; B = w1b [768,192] bf16 (n,k row-major -> B-frag natural)
__global__ __launch_bounds__(256) void k_gemm1(
    const short* __restrict__ xn2, const short* __restrict__ w1b,
    const float* __restrict__ b1h, short* __restrict__ hid) {
  __shared__ __align__(16) short As[128 * 72];
  __shared__ __align__(16) short Bs[128 * 72];
  int m0 = blockIdx.x * 128, n0 = blockIdx.y * 128, tid = threadIdx.x;
  int lane = tid & 63, l16 = lane & 15, quad = lane >> 4;
  int wm = (tid >> 6) >> 1, wn = (tid >> 6) & 1;
  f32x4 acc[4][4] = {};
  for (int kt = 0; kt < 3; kt++) {
    int kb = kt * 64;
    for (int i = tid; i < 1024; i += 256) {
      int row = i >> 3, c8 = (i & 7) * 8;
      *(float4*)&As[row * 72 + c8] = *(const float4*)&xn2[(size_t)(m0 + row) * 192 + kb + c8];
      *(float4*)&Bs[row * 72 + c8] = *(const float4*)&w1b[(size_t)(n0 + row) * 192 + kb + c8];
    }
    __syncthreads();
#pragma unroll
    for (int ks = 0; ks < 2; ks++) {
      int ko = ks * 32 + quad * 8;
      bf16x8 a[4], b[4];
#pragma unroll
      for (int mi = 0; mi < 4; mi++) a[mi] = *(const bf16x8*)&As[(wm * 64 + mi * 16 + l16) * 72 + ko];
#pragma unroll
      for (int ni = 0; ni < 4; ni++) b[ni] = *(const bf16x8*)&Bs[(wn * 64 + ni * 16 + l16) * 72 + ko];
#pragma unroll
      for (int mi = 0; mi < 4; mi++)
#pragma unroll
        for (int ni = 0; ni < 4; ni++)
          acc[mi][ni] = __builtin_amdgcn_mfma_f32_16x16x32_bf16(a[mi], b[ni], acc[mi][ni], 0, 0, 0);
    }
    __syncthreads();
  }
#pragma unroll
  for (int ni = 0; ni < 4; ni++) {
    int n = n0 + wn * 64 + ni * 16 + l16;
    float bias = b1h[n];
#pragma unroll
    for (int mi = 0; mi < 4; mi++)
#pragma unroll
      for (int r = 0; r < 4; r++) {
        int m = m0 + wm * 64 + mi * 16 + quad * 4 + r;
        float v = acc[mi][ni][r] + bias;
        float g = 0.5f * v * (1.f + erff(v * 0.70710678118f));
        hid[(size_t)m * 768 + n] = f2b(g);
      }
  }
}

// ---- K11: MFMA GEMM2 (swapped): D[d][l] = w2 @ hid^T; out = xr + a*(D+b) ----
// A = w2b [192,768] (m=d, k); B = hid [32768,768] (n=l, k) -> coalesced NCHW store
__global__ __launch_bounds__(256) void k_gemm2(
    const short* __restrict__ hid, const short* __restrict__ w2b,
    const float* __restrict__ b2o, const float* __restrict__ xr,
    const float* __restrict__ am, float* __restrict__ out) {
  __shared__ __align__(16) short Wt[192 * 72];
  __shared__ __align__(16) short Ht[64 * 72];
  int l0g = blockIdx.x * 64, tid = threadIdx.x;
  int lane = tid & 63, l16 = lane & 15, quad = lane >> 4;
  int wm = (tid >> 6) >> 1, wn = (tid >> 6) & 1;  // wm: d-half(96), wn: l-half(32)
  f32x4 acc[6][2] = {};
  for (int kt = 0; kt < 12; kt++) {
    int kb = kt * 64;
    for (int i = tid; i < 1536; i += 256) {
      int row = i >> 3, c8 = (i & 7) * 8;
      *(float4*)&Wt[row * 72 + c8] = *(const float4*)&w2b[(size_t)row * 768 + kb + c8];
    }
    for (int i = tid; i < 512; i += 256) {
      int row = i >> 3, c8 = (i & 7) * 8;
      *(float4*)&Ht[row * 72 + c8] = *(const float4*)&hid[(size_t)(l0g + row) * 768 + kb + c8];
    }
    __syncthreads();
#pragma unroll
    for (int ks = 0; ks < 2; ks++) {
      int ko = ks * 32 + quad * 8;
      bf16x8 a[6], b[2];
#pragma unroll
      for (int mi = 0; mi < 6; mi++) a[mi] = *(const bf16x8*)&Wt[(wm * 96 + mi * 16 + l16) * 72 + ko];
#pragma unroll
      for (int ni = 0; ni < 2; ni++) b[ni] = *(const bf16x8*)&Ht[(wn * 32 + ni * 16 + l16) * 72 + ko];
#pragma unroll
      for (int mi = 0; mi < 6; mi++)
#pragma unroll
        for (int ni = 0; ni < 2; ni++)
          acc[mi][ni] = __builtin_amdgcn_mfma_f32_16x16x32_bf16(a[mi], b[ni], acc[mi][ni], 0, 0, 0);
    }
    __syncthreads();
  }
  float alpha = am[0];
#pragma unroll
  for (int mi = 0; mi < 6; mi++)
#pragma unroll
    for (int r = 0; r < 4; r++) {
      int d = wm * 96 + mi * 16 + quad * 4 + r;
      float bias = b2o[d];
#pragma unroll
      for (int ni = 0; ni < 2; ni++) {
        int lg = l0g + wn * 32 + ni * 16 + l16;
        size_t idx = ((size_t)(lg >> 12) * Dm + d) * Ln + (lg & 4095);
        out[idx] = xr[idx] + alpha * (acc[mi][ni][r] + bias);
      }
    }
}

extern "C" void kernel_launch(void* const* d_in, const int* in_sizes, int n_in,
                              void* d_out, int out_size, void* d_ws, size_t ws_size,
                              hipStream_t stream) {
  (void)in_sizes; (void)n_in; (void)out_size; (void)ws_size;
  const float* x     = (const float*)d_in[0];
  const float* ln1_g = (const float*)d_in[1];
  const float* ln1_b = (const float*)d_in[2];
  const float* ln2_g = (const float*)d_in[3];
  const float* ln2_b = (const float*)d_in[4];
  const float* dw_w  = (const float*)d_in[5];
  const float* bn_g  = (const float*)d_in[6];
  const float* bn_b  = (const float*)d_in[7];
  const float* bn_rm = (const float*)d_in[8];
  const float* bn_rv = (const float*)d_in[9];
  const float* ssm_g = (const float*)d_in[10];
  const float* ssm_b = (const float*)d_in[11];
  const float* xp_w  = (const float*)d_in[12];
  const float* xp_b  = (const float*)d_in[13];
  const float* dt_w  = (const float*)d_in[14];
  const float* dt_b  = (const float*)d_in[15];
  const float* A_log = (const float*)d_in[16];
  const float* B_w   = (const float*)d_in[17];
  const float* C_w   = (const float*)d_in[18];
  const float* Dp    = (const float*)d_in[19];
  const float* out_w = (const float*)d_in[20];
  const float* out_b = (const float*)d_in[21];
  const float* w1    = (const float*)d_in[22];
  const float* b1    = (const float*)d_in[23];
  const float* w2    = (const float*)d_in[24];
  const float* b2    = (const float*)d_in[25];
  const float* a_loc = (const float*)d_in[26];
  const float* a_ssm = (const float*)d_in[27];
  const float* a_mlp = (const float*)d_in[28];

  float* ws = (float*)d_ws;
  float* xn      = ws;
  float* xln1    = ws + 6291456;
  float* abc     = ws + 12582912;
  float* yb      = ws + 18874368;
  float* xr      = ws + 20971520;
  float* sums    = ws + 27262976;
  float* carries = ws + 27295744;
  float* sout = xn;                         // xn dead after k_proj
  short* xn2  = (short*)ws;                 // xn/sout dead after k_conv
  short* hid  = (short*)(ws + 6291456);     // xln1+abc dead after k_conv (exactly 12582912 floats)
  short* w1b  = (short*)(ws + 18874368);    // yb dead after k_out
  short* w2b  = w1b + 147456;
  float* out = (float*)d_out;

  k_ln   <<<dim3(64, 8),   256, 0, stream>>>(x, ln1_g, ln1_b, ssm_g, ssm_b, xn, xln1);
  k_proj <<<dim3(1024),    256, 0, stream>>>(xn, dt_w, dt_b, B_w, C_w, xp_w, xp_b, A_log, abc);
  k_scan1<<<dim3(32, 8),    64, 0, stream>>>(abc, sums);
  k_scan2<<<dim3(1),       512, 0, stream>>>(sums, carries);
  k_scan3<<<dim3(32, 8),    64, 0, stream>>>(abc, carries, yb);
  k_out  <<<dim3(128, 8),  256, 0, stream>>>(yb, out_w, out_b, Dp, xln1, sout);
  k_wconv<<<dim3(288),     256, 0, stream>>>(w1, w2, w1b);
  k_conv <<<dim3(192, 8),  256, 0, stream>>>(x, dw_w, bn_g, bn_b, bn_rm, bn_rv, sout, a_loc, a_ssm, xr);
  k_ln2  <<<dim3(64, 8),   256, 0, stream>>>(xr, ln2_g, ln2_b, xn2);
  k_gemm1<<<dim3(256, 6),  256, 0, stream>>>(xn2, w1b, b1, hid);
  k_gemm2<<<dim3(512),     256, 0, stream>>>(hid, w2b, b2, xr, a_mlp, out);
}

// Round 3
// 326.232 us; speedup vs baseline: 3.7212x; 1.3074x over previous
//
#include <hip/hip_runtime.h>
#include <hip/hip_bf16.h>
#include <math.h>

// MambaBlock fused pipeline v3: MFMA everywhere matmul-shaped.
// ws layout (floats):
//   xnb   bf16 [32768,192] @ 0          (3145728 f)   -> dead after k_proj; xn2 aliases
//   xln1b bf16 [32768,192] @ 3145728    (3145728 f)
//   abc   f32  [32768,192] @ 6291456    (6291456 f)   -> dead after scan3; hid aliases
//   y     bf16 [32768,64]  @ 12582912   (1048576 f)   -> dead after k_out
//   sums  f32  [8*64*2*64] @ 13631488   (65536 f)
//   carr  f32  [8*64*64]   @ 13697024   (32768 f)
//   sout  f32  [8,192,4096]@ 13729792   (6291456 f)   -> dead after k_conv
//   xr    f32  [8,192,4096]@ 20021248   (6291456 f)
//   wb    bf16 weights     @ 26312704   (178176 f)
// hid bf16 [32768,768] aliases [6291456..18874368) — all residents dead by k_gemm1.

#define DEV static __device__ __forceinline__

constexpr int Bn = 8, Dm = 192, Ln = 4096, Sn = 64, Hd = 768;

typedef __attribute__((ext_vector_type(8))) short bf16x8;
typedef __attribute__((ext_vector_type(4))) float f32x4;

DEV float wave_sum(float v) {
#pragma unroll
  for (int off = 1; off < 64; off <<= 1) v += __shfl_xor(v, off);
  return v;
}

DEV short f2b(float x) {
  __hip_bfloat16 h = __float2bfloat16(x);
  return *(short*)&h;
}

DEV float b2f(short x) {
  __hip_bfloat16 h = *(__hip_bfloat16*)&x;
  return __bfloat162float(h);
}

// ---- K1: transpose + ln1 + ssm_ln -> bf16 xn, bf16 xln1 --------------------
__global__ __launch_bounds__(256) void k_ln(
    const float* __restrict__ x, const float* __restrict__ g1, const float* __restrict__ b1,
    const float* __restrict__ g2, const float* __restrict__ b2,
    short* __restrict__ xnb, short* __restrict__ xln1b) {
  __shared__ __align__(16) float tile[Dm * 65];
  int b = blockIdx.y, l0 = blockIdx.x * 64, tid = threadIdx.x;
  const float* xb = x + (size_t)b * Dm * Ln;
  for (int i = tid; i < Dm * 16; i += 256) {
    int d = i >> 4, l4 = (i & 15) << 2;
    float4 v = *(const float4*)&xb[d * Ln + l0 + l4];
    tile[d * 65 + l4]     = v.x; tile[d * 65 + l4 + 1] = v.y;
    tile[d * 65 + l4 + 2] = v.z; tile[d * 65 + l4 + 3] = v.w;
  }
  __syncthreads();
  int lane = tid & 63, wv = tid >> 6;
  float ga0 = g1[lane], ga1 = g1[lane + 64], ga2 = g1[lane + 128];
  float bb0 = b1[lane], bb1 = b1[lane + 64], bb2 = b1[lane + 128];
  float gc0 = g2[lane], gc1 = g2[lane + 64], gc2 = g2[lane + 128];
  float bc0 = b2[lane], bc1 = b2[lane + 64], bc2 = b2[lane + 128];
  for (int li = wv; li < 64; li += 4) {
    float v0 = tile[lane * 65 + li], v1 = tile[(lane + 64) * 65 + li], v2 = tile[(lane + 128) * 65 + li];
    float s  = wave_sum(v0 + v1 + v2);
    float sq = wave_sum(v0 * v0 + v1 * v1 + v2 * v2);
    float m = s * (1.f / 192.f);
    float inv = rsqrtf(sq * (1.f / 192.f) - m * m + 1e-5f);
    float y0 = (v0 - m) * inv * ga0 + bb0;
    float y1 = (v1 - m) * inv * ga1 + bb1;
    float y2 = (v2 - m) * inv * ga2 + bb2;
    float s2  = wave_sum(y0 + y1 + y2);
    float sq2 = wave_sum(y0 * y0 + y1 * y1 + y2 * y2);
    float m2 = s2 * (1.f / 192.f);
    float inv2 = rsqrtf(sq2 * (1.f / 192.f) - m2 * m2 + 1e-5f);
    size_t base = ((size_t)b * Ln + l0 + li) * Dm;
    xln1b[base + lane]       = f2b(y0);
    xln1b[base + lane + 64]  = f2b(y1);
    xln1b[base + lane + 128] = f2b(y2);
    xnb[base + lane]       = f2b((y0 - m2) * inv2 * gc0 + bc0);
    xnb[base + lane + 64]  = f2b((y1 - m2) * inv2 * gc1 + bc1);
    xnb[base + lane + 128] = f2b((y2 - m2) * inv2 * gc2 + bc2);
  }
}

// ---- K2: weights -> bf16 (dt|B|C|xp cat, out_w, w1, w2) --------------------
__global__ __launch_bounds__(256) void k_wconv(
    const float* __restrict__ dt_w, const float* __restrict__ B_w,
    const float* __restrict__ C_w, const float* __restrict__ xp_w,
    const float* __restrict__ out_w, const float* __restrict__ w1,
    const float* __restrict__ w2, short* __restrict__ wb) {
  int i = blockIdx.x * 256 + threadIdx.x;  // 89088 float4 groups total
  const float4* src;
  if (i < 3072)       src = (const float4*)dt_w + i;
  else if (i < 6144)  src = (const float4*)B_w + (i - 3072);
  else if (i < 9216)  src = (const float4*)C_w + (i - 6144);
  else if (i < 12288) src = (const float4*)xp_w + (i - 9216);
  else if (i < 15360) src = (const float4*)out_w + (i - 12288);
  else if (i < 52224) src = (const float4*)w1 + (i - 15360);
  else                src = (const float4*)w2 + (i - 52224);
  float4 v = *src;
  int o = i * 4;
  wb[o]     = f2b(v.x); wb[o + 1] = f2b(v.y);
  wb[o + 2] = f2b(v.z); wb[o + 3] = f2b(v.w);
}

// ---- K3: MFMA proj GEMM [32768x256, K=192] + in-register SSM epilogue ------
// Each wave: 32 rows x all 256 cols => dt/B/C/xp for same state s live in the
// same lane (tiles ni, ni+4, ni+8, ni+12) -> no cross-lane epilogue.
__global__ __launch_bounds__(256) void k_proj(
    const short* __restrict__ xnb, const short* __restrict__ wcat,
    const float* __restrict__ dt_b, const float* __restrict__ xp_b,
    const float* __restrict__ A_log, float* __restrict__ abc) {
  __shared__ __align__(16) short As[128 * 72];
  __shared__ __align__(16) short Bs[256 * 72];
  int m0 = blockIdx.x * 128, tid = threadIdx.x;
  int lane = tid & 63, l16 = lane & 15, quad = lane >> 4, w = tid >> 6;
  f32x4 acc[2][16] = {};
  for (int kt = 0; kt < 3; kt++) {
    int kb = kt * 64;
    for (int i = tid; i < 1024; i += 256) {
      int row = i >> 3, c8 = (i & 7) * 8;
      *(float4*)&As[row * 72 + c8] = *(const float4*)&xnb[(size_t)(m0 + row) * 192 + kb + c8];
    }
    for (int i = tid; i < 2048; i += 256) {
      int row = i >> 3, c8 = (i & 7) * 8;
      *(float4*)&Bs[row * 72 + c8] = *(const float4*)&wcat[(size_t)row * 192 + kb + c8];
    }
    __syncthreads();
#pragma unroll
    for (int ks = 0; ks < 2; ks++) {
      int ko = ks * 32 + quad * 8;
      bf16x8 a0 = *(const bf16x8*)&As[(w * 32 + l16) * 72 + ko];
      bf16x8 a1 = *(const bf16x8*)&As[(w * 32 + 16 + l16) * 72 + ko];
#pragma unroll
      for (int nh = 0; nh < 2; nh++) {
        bf16x8 bfr[8];
#pragma unroll
        for (int j = 0; j < 8; j++) bfr[j] = *(const bf16x8*)&Bs[((nh * 8 + j) * 16 + l16) * 72 + ko];
#pragma unroll
        for (int j = 0; j < 8; j++) {
          acc[0][nh * 8 + j] = __builtin_amdgcn_mfma_f32_16x16x32_bf16(a0, bfr[j], acc[0][nh * 8 + j], 0, 0, 0);
          acc[1][nh * 8 + j] = __builtin_amdgcn_mfma_f32_16x16x32_bf16(a1, bfr[j], acc[1][nh * 8 + j], 0, 0, 0);
        }
      }
    }
    __syncthreads();
  }
  float Av[4], dtb[4], xpb[4];
#pragma unroll
  for (int ni = 0; ni < 4; ni++) {
    int s = ni * 16 + l16;
    Av[ni] = -expf(A_log[s]); dtb[ni] = dt_b[s]; xpb[ni] = xp_b[s];
  }
#pragma unroll
  for (int mi = 0; mi < 2; mi++)
#pragma unroll
    for (int r = 0; r < 4; r++) {
      int m = m0 + w * 32 + mi * 16 + quad * 4 + r;
      float* orow = abc + (size_t)m * 192;
#pragma unroll
      for (int ni = 0; ni < 4; ni++) {
        int s = ni * 16 + l16;
        float z = acc[mi][ni][r] + dtb[ni];
        float sp = (z > 20.f) ? z : log1pf(expf(z));
        float delta = sp * 0.01f + 0.0001f;
        float bt  = acc[mi][ni + 4][r];
        float ct  = acc[mi][ni + 8][r];
        float xpv = acc[mi][ni + 12][r] + xpb[ni];
        float dA = fminf(fmaxf(delta * Av[ni], -10.f), -0.0001f);
        float Ae = fminf(fmaxf(expf(dA), 0.001f), 0.999f) + 1e-10f;
        orow[s]       = Ae;
        orow[64 + s]  = delta * bt * xpv;
        orow[128 + s] = ct;
      }
    }
}

// ---- K4: scan phase 1 (64-step chunk summaries) ----------------------------
__global__ __launch_bounds__(64) void k_scan1(const float* __restrict__ abc, float* __restrict__ sums) {
  int c = blockIdx.x, b = blockIdx.y, s = threadIdx.x;
  const float* p = abc + ((size_t)b * Ln + c * 64) * 192;
  float prodA = 1.f, h = 0.f;
  int t = 0;
  if (c == 0) { prodA = p[s]; h = p[64 + s]; t = 1; }
#pragma unroll 4
  for (; t < 64; t++) {
    float a = p[t * 192 + s], bx = p[t * 192 + 64 + s];
    h = a * (h + bx);
    prodA *= a;
  }
  int ci = b * 64 + c;
  sums[(ci * 2 + 0) * 64 + s] = prodA;
  sums[(ci * 2 + 1) * 64 + s] = h;
}

// ---- K5: scan phase 2 (carry chain over 64 chunks) -------------------------
__global__ __launch_bounds__(512) void k_scan2(const float* __restrict__ sums, float* __restrict__ carries) {
  int tid = threadIdx.x, b = tid >> 6, s = tid & 63;
  float cur = 0.f;
  for (int c = 0; c < 64; c++) {
    int ci = b * 64 + c;
    carries[ci * 64 + s] = cur;
    cur = sums[(ci * 2 + 0) * 64 + s] * cur + sums[(ci * 2 + 1) * 64 + s];
  }
}

// ---- K6: scan phase 3 (replay, y = C*h -> bf16) ----------------------------
__global__ __launch_bounds__(64) void k_scan3(const float* __restrict__ abc, const float* __restrict__ carries,
                                              short* __restrict__ y) {
  int c = blockIdx.x, b = blockIdx.y, s = threadIdx.x;
  size_t r0 = (size_t)b * Ln + c * 64;
  const float* p = abc + r0 * 192;
  short* yo = y + r0 * 64;
  float h = carries[(b * 64 + c) * 64 + s];
  int t = 0;
  if (c == 0) { h = p[64 + s]; yo[s] = f2b(p[128 + s] * h); t = 1; }
#pragma unroll 4
  for (; t < 64; t++) {
    float a = p[t * 192 + s], bx = p[t * 192 + 64 + s], ct = p[t * 192 + 128 + s];
    h = a * (h + bx);
    yo[t * 64 + s] = f2b(ct * h);
  }
}

// ---- K7: MFMA out-proj (swapped): sout[d][l] = out_w @ y^T + b (+D skip) ---
__global__ __launch_bounds__(256) void k_out(
    const short* __restrict__ y, const short* __restrict__ owb, const float* __restrict__ out_b,
    const float* __restrict__ Dp, const short* __restrict__ xln1b, float* __restrict__ sout) {
  __shared__ __align__(16) short As[192 * 72];
  __shared__ __align__(16) short Bs[128 * 72];
  int l0g = blockIdx.x * 128, tid = threadIdx.x;
  int lane = tid & 63, l16 = lane & 15, quad = lane >> 4;
  int wm = (tid >> 6) >> 1, wn = (tid >> 6) & 1;
  f32x4 acc[6][4] = {};
  for (int i = tid; i < 1536; i += 256) {
    int row = i >> 3, c8 = (i & 7) * 8;
    *(float4*)&As[row * 72 + c8] = *(const float4*)&owb[row * 64 + c8];
  }
  for (int i = tid; i < 1024; i += 256) {
    int row = i >> 3, c8 = (i & 7) * 8;
    *(float4*)&Bs[row * 72 + c8] = *(const float4*)&y[(size_t)(l0g + row) * 64 + c8];
  }
  __syncthreads();
#pragma unroll
  for (int ks = 0; ks < 2; ks++) {
    int ko = ks * 32 + quad * 8;
    bf16x8 a[6], b[4];
#pragma unroll
    for (int mi = 0; mi < 6; mi++) a[mi] = *(const bf16x8*)&As[(wm * 96 + mi * 16 + l16) * 72 + ko];
#pragma unroll
    for (int ni = 0; ni < 4; ni++) b[ni] = *(const bf16x8*)&Bs[(wn * 64 + ni * 16 + l16) * 72 + ko];
#pragma unroll
    for (int mi = 0; mi < 6; mi++)
#pragma unroll
      for (int ni = 0; ni < 4; ni++)
        acc[mi][ni] = __builtin_amdgcn_mfma_f32_16x16x32_bf16(a[mi], b[ni], acc[mi][ni], 0, 0, 0);
  }
  int bb = l0g >> 12;
#pragma unroll
  for (int mi = 0; mi < 6; mi++)
#pragma unroll
    for (int r = 0; r < 4; r++) {
      int d = wm * 96 + mi * 16 + quad * 4 + r;
      float ob = out_b[d];
      float dc = fminf(fmaxf(Dp[d], -2.f), 2.f);
#pragma unroll
      for (int ni = 0; ni < 4; ni++) {
        int l = l0g + wn * 64 + ni * 16 + l16;
        float v = acc[mi][ni][r] + ob;
        if (dc != 0.f) v += dc * b2f(xln1b[(size_t)l * 192 + d]);
        sout[((size_t)bb * Dm + d) * Ln + (l & 4095)] = v;
      }
    }
}

// ---- K8: depthwise conv 3x3 + BN + residual combine -> xr (NCHW) -----------
__global__ __launch_bounds__(256) void k_conv(
    const float* __restrict__ x, const float* __restrict__ dw,
    const float* __restrict__ bn_g, const float* __restrict__ bn_b,
    const float* __restrict__ bn_rm, const float* __restrict__ bn_rv,
    const float* __restrict__ sout, const float* __restrict__ a_loc,
    const float* __restrict__ a_ssm, float* __restrict__ xr) {
  __shared__ __align__(16) float xs[64 * 64];
  int d = blockIdx.x, b = blockIdx.y, tid = threadIdx.x;
  const float* xp = x + ((size_t)b * Dm + d) * Ln;
  for (int i = tid; i < 1024; i += 256) ((float4*)xs)[i] = ((const float4*)xp)[i];
  __syncthreads();
  float w[9];
#pragma unroll
  for (int k = 0; k < 9; k++) w[k] = dw[d * 9 + k];
  float scale = bn_g[d] * rsqrtf(bn_rv[d] + 1e-5f);
  float rm = bn_rm[d], bb = bn_b[d];
  float al = a_loc[0], as_ = a_ssm[0];
  const float* sp = sout + ((size_t)b * Dm + d) * Ln;
  float* xo = xr + ((size_t)b * Dm + d) * Ln;
  for (int i = tid; i < 4096; i += 256) {
    int h = i >> 6, wc = i & 63;
    float acc = 0.f;
#pragma unroll
    for (int kh = 0; kh < 3; kh++) {
      int hh = h + kh - 1;
      if (hh < 0 || hh >= 64) continue;
#pragma unroll
      for (int kw = 0; kw < 3; kw++) {
        int ww2 = wc + kw - 1;
        if (ww2 < 0 || ww2 >= 64) continue;
        acc += xs[hh * 64 + ww2] * w[kh * 3 + kw];
      }
    }
    float xl = (acc - rm) * scale + bb;
    xo[i] = xs[i] + al * xl + as_ * sp[i];
  }
}

// ---- K9: ln2 -> bf16 xn2 [B*L, 192] row-major ------------------------------
__global__ __launch_bounds__(256) void k_ln2(
    const float* __restrict__ xr, const float* __restrict__ g, const float* __restrict__ bb,
    short* __restrict__ xn2) {
  __shared__ __align__(16) float tile[Dm * 65];
  int b = blockIdx.y, l0 = blockIdx.x * 64, tid = threadIdx.x;
  const float* xb = xr + (size_t)b * Dm * Ln;
  for (int i = tid; i < Dm * 16; i += 256) {
    int d = i >> 4, l4 = (i & 15) << 2;
    float4 v = *(const float4*)&xb[d * Ln + l0 + l4];
    tile[d * 65 + l4]     = v.x; tile[d * 65 + l4 + 1] = v.y;
    tile[d * 65 + l4 + 2] = v.z; tile[d * 65 + l4 + 3] = v.w;
  }
  __syncthreads();
  int lane = tid & 63, wv = tid >> 6;
  float g0 = g[lane], g1v = g[lane + 64], g2v = g[lane + 128];
  float b0 = bb[lane], b1v = bb[lane + 64], b2v = bb[lane + 128];
  for (int li = wv; li < 64; li += 4) {
    float v0 = tile[lane * 65 + li], v1 = tile[(lane + 64) * 65 + li], v2 = tile[(lane + 128) * 65 + li];
    float s  = wave_sum(v0 + v1 + v2);
    float sq = wave_sum(v0 * v0 + v1 * v1 + v2 * v2);
    float m = s * (1.f / 192.f);
    float inv = rsqrtf(sq * (1.f / 192.f) - m * m + 1e-5f);
    size_t base = ((size_t)b * Ln + l0 + li) * Dm;
    xn2[base + lane]       = f2b((v0 - m) * inv * g0 + b0);
    xn2[base + lane + 64]  = f2b((v1 - m) * inv * g1v + b1v);
    xn2[base + lane + 128] = f2b((v2 - m) * inv * g2v + b2v);
  }
}

// ---- K10: MFMA GEMM1: hid = gelu(xn2 @ w1^T + b1), bf16 out ----------------
__global__ __launch_bounds__(256) void k_gemm1(
    const short* __restrict__ xn2, const short* __restrict__ w1b,
    const float* __restrict__ b1h, short* __restrict__ hid) {
  __shared__ __align__(16) short As[128 * 72];
  __shared__ __align__(16) short Bs[128 * 72];
  int m0 = blockIdx.x * 128, n0 = blockIdx.y * 128, tid = threadIdx.x;
  int lane = tid & 63, l16 = lane & 15, quad = lane >> 4;
  int wm = (tid >> 6) >> 1, wn = (tid >> 6) & 1;
  f32x4 acc[4][4] = {};
  for (int kt = 0; kt < 3; kt++) {
    int kb = kt * 64;
    for (int i = tid; i < 1024; i += 256) {
      int row = i >> 3, c8 = (i & 7) * 8;
      *(float4*)&As[row * 72 + c8] = *(const float4*)&xn2[(size_t)(m0 + row) * 192 + kb + c8];
      *(float4*)&Bs[row * 72 + c8] = *(const float4*)&w1b[(size_t)(n0 + row) * 192 + kb + c8];
    }
    __syncthreads();
#pragma unroll
    for (int ks = 0; ks < 2; ks++) {
      int ko = ks * 32 + quad * 8;
      bf16x8 a[4], b[4];
#pragma unroll
      for (int mi = 0; mi < 4; mi++) a[mi] = *(const bf16x8*)&As[(wm * 64 + mi * 16 + l16) * 72 + ko];
#pragma unroll
      for (int ni = 0; ni < 4; ni++) b[ni] = *(const bf16x8*)&Bs[(wn * 64 + ni * 16 + l16) * 72 + ko];
#pragma unroll
      for (int mi = 0; mi < 4; mi++)
#pragma unroll
        for (int ni = 0; ni < 4; ni++)
          acc[mi][ni] = __builtin_amdgcn_mfma_f32_16x16x32_bf16(a[mi], b[ni], acc[mi][ni], 0, 0, 0);
    }
    __syncthreads();
  }
#pragma unroll
  for (int ni = 0; ni < 4; ni++) {
    int n = n0 + wn * 64 + ni * 16 + l16;
    float bias = b1h[n];
#pragma unroll
    for (int mi = 0; mi < 4; mi++)
#pragma unroll
      for (int r = 0; r < 4; r++) {
        int m = m0 + wm * 64 + mi * 16 + quad * 4 + r;
        float v = acc[mi][ni][r] + bias;
        float g = 0.5f * v * (1.f + erff(v * 0.70710678118f));
        hid[(size_t)m * 768 + n] = f2b(g);
      }
  }
}

// ---- K11: MFMA GEMM2 (swapped): D[d][l] = w2 @ hid^T; out = xr + a*(D+b) ----
__global__ __launch_bounds__(256) void k_gemm2(
    const short* __restrict__ hid, const short* __restrict__ w2b,
    const float* __restrict__ b2o, const float* __restrict__ xr,
    const float* __restrict__ am, float* __restrict__ out) {
  __shared__ __align__(16) short Wt[192 * 72];
  __shared__ __align__(16) short Ht[64 * 72];
  int l0g = blockIdx.x * 64, tid = threadIdx.x;
  int lane = tid & 63, l16 = lane & 15, quad = lane >> 4;
  int wm = (tid >> 6) >> 1, wn = (tid >> 6) & 1;
  f32x4 acc[6][2] = {};
  for (int kt = 0; kt < 12; kt++) {
    int kb = kt * 64;
    for (int i = tid; i < 1536; i += 256) {
      int row = i >> 3, c8 = (i & 7) * 8;
      *(float4*)&Wt[row * 72 + c8] = *(const float4*)&w2b[(size_t)row * 768 + kb + c8];
    }
    for (int i = tid; i < 512; i += 256) {
      int row = i >> 3, c8 = (i & 7) * 8;
      *(float4*)&Ht[row * 72 + c8] = *(const float4*)&hid[(size_t)(l0g + row) * 768 + kb + c8];
    }
    __syncthreads();
#pragma unroll
    for (int ks = 0; ks < 2; ks++) {
      int ko = ks * 32 + quad * 8;
      bf16x8 a[6], b[2];
#pragma unroll
      for (int mi = 0; mi < 6; mi++) a[mi] = *(const bf16x8*)&Wt[(wm * 96 + mi * 16 + l16) * 72 + ko];
#pragma unroll
      for (int ni = 0; ni < 2; ni++) b[ni] = *(const bf16x8*)&Ht[(wn * 32 + ni * 16 + l16) * 72 + ko];
#pragma unroll
      for (int mi = 0; mi < 6; mi++)
#pragma unroll
        for (int ni = 0; ni < 2; ni++)
          acc[mi][ni] = __builtin_amdgcn_mfma_f32_16x16x32_bf16(a[mi], b[ni], acc[mi][ni], 0, 0, 0);
    }
    __syncthreads();
  }
  float alpha = am[0];
#pragma unroll
  for (int mi = 0; mi < 6; mi++)
#pragma unroll
    for (int r = 0; r < 4; r++) {
      int d = wm * 96 + mi * 16 + quad * 4 + r;
      float bias = b2o[d];
#pragma unroll
      for (int ni = 0; ni < 2; ni++) {
        int lg = l0g + wn * 32 + ni * 16 + l16;
        size_t idx = ((size_t)(lg >> 12) * Dm + d) * Ln + (lg & 4095);
        out[idx] = xr[idx] + alpha * (acc[mi][ni][r] + bias);
      }
    }
}

extern "C" void kernel_launch(void* const* d_in, const int* in_sizes, int n_in,
                              void* d_out, int out_size, void* d_ws, size_t ws_size,
                              hipStream_t stream) {
  (void)in_sizes; (void)n_in; (void)out_size; (void)ws_size;
  const float* x     = (const float*)d_in[0];
  const float* ln1_g = (const float*)d_in[1];
  const float* ln1_b = (const float*)d_in[2];
  const float* ln2_g = (const float*)d_in[3];
  const float* ln2_b = (const float*)d_in[4];
  const float* dw_w  = (const float*)d_in[5];
  const float* bn_g  = (const float*)d_in[6];
  const float* bn_b  = (const float*)d_in[7];
  const float* bn_rm = (const float*)d_in[8];
  const float* bn_rv = (const float*)d_in[9];
  const float* ssm_g = (const float*)d_in[10];
  const float* ssm_b = (const float*)d_in[11];
  const float* xp_w  = (const float*)d_in[12];
  const float* xp_b  = (const float*)d_in[13];
  const float* dt_w  = (const float*)d_in[14];
  const float* dt_b  = (const float*)d_in[15];
  const float* A_log = (const float*)d_in[16];
  const float* B_w   = (const float*)d_in[17];
  const float* C_w   = (const float*)d_in[18];
  const float* Dp    = (const float*)d_in[19];
  const float* out_w = (const float*)d_in[20];
  const float* out_b = (const float*)d_in[21];
  const float* w1    = (const float*)d_in[22];
  const float* b1    = (const float*)d_in[23];
  const float* w2    = (const float*)d_in[24];
  const float* b2    = (const float*)d_in[25];
  const float* a_loc = (const float*)d_in[26];
  const float* a_ssm = (const float*)d_in[27];
  const float* a_mlp = (const float*)d_in[28];

  float* ws = (float*)d_ws;
  short* xnb   = (short*)ws;
  short* xln1b = (short*)(ws + 3145728);
  float* abc   = ws + 6291456;
  short* yB    = (short*)(ws + 12582912);
  float* sums  = ws + 13631488;
  float* carr  = ws + 13697024;
  float* sout  = ws + 13729792;
  float* xr    = ws + 20021248;
  short* wb    = (short*)(ws + 26312704);
  short* wcatb = wb;            // [256,192]
  short* owb   = wb + 49152;    // [192,64]
  short* w1b   = wb + 61440;    // [768,192]
  short* w2b   = wb + 208896;   // [192,768]
  short* xn2   = (short*)ws;               // aliases xnb (dead after k_proj)
  short* hid   = (short*)(ws + 6291456);   // aliases abc..sout head (dead by then)
  float* out   = (float*)d_out;

  k_ln   <<<dim3(64, 8),  256, 0, stream>>>(x, ln1_g, ln1_b, ssm_g, ssm_b, xnb, xln1b);
  k_wconv<<<dim3(348),    256, 0, stream>>>(dt_w, B_w, C_w, xp_w, out_w, w1, w2, wb);
  k_proj <<<dim3(256),    256, 0, stream>>>(xnb, wcatb, dt_b, xp_b, A_log, abc);
  k_scan1<<<dim3(64, 8),   64, 0, stream>>>(abc, sums);
  k_scan2<<<dim3(1),      512, 0, stream>>>(sums, carr);
  k_scan3<<<dim3(64, 8),   64, 0, stream>>>(abc, carr, yB);
  k_out  <<<dim3(256),    256, 0, stream>>>(yB, owb, out_b, Dp, xln1b, sout);
  k_conv <<<dim3(192, 8), 256, 0, stream>>>(x, dw_w, bn_g, bn_b, bn_rm, bn_rv, sout, a_loc, a_ssm, xr);
  k_ln2  <<<dim3(64, 8),  256, 0, stream>>>(xr, ln2_g, ln2_b, xn2);
  k_gemm1<<<dim3(256, 6), 256, 0, stream>>>(xn2, w1b, b1, hid);
  k_gemm2<<<dim3(512),    256, 0, stream>>>(hid, w2b, b2, xr, a_mlp, out);
}

// Round 4
// 323.066 us; speedup vs baseline: 3.7576x; 1.0098x over previous
//
#include <hip/hip_runtime.h>
#include <hip/hip_bf16.h>
#include <math.h>

// MambaBlock fused pipeline v4: coalesced gemm1 stores, pad-88 LDS, wider gemm2 tile.
// ws layout (floats): see v3 comments — unchanged.

#define DEV static __device__ __forceinline__

constexpr int Bn = 8, Dm = 192, Ln = 4096, Sn = 64, Hd = 768;

typedef __attribute__((ext_vector_type(8))) short bf16x8;
typedef __attribute__((ext_vector_type(4))) float f32x4;

DEV float wave_sum(float v) {
#pragma unroll
  for (int off = 1; off < 64; off <<= 1) v += __shfl_xor(v, off);
  return v;
}

DEV short f2b(float x) {
  __hip_bfloat16 h = __float2bfloat16(x);
  return *(short*)&h;
}

DEV float b2f(short x) {
  __hip_bfloat16 h = *(__hip_bfloat16*)&x;
  return __bfloat162float(h);
}

// ---- K1: transpose + ln1 + ssm_ln -> bf16 xn, bf16 xln1 --------------------
__global__ __launch_bounds__(256) void k_ln(
    const float* __restrict__ x, const float* __restrict__ g1, const float* __restrict__ b1,
    const float* __restrict__ g2, const float* __restrict__ b2,
    short* __restrict__ xnb, short* __restrict__ xln1b) {
  __shared__ __align__(16) float tile[Dm * 65];
  int b = blockIdx.y, l0 = blockIdx.x * 64, tid = threadIdx.x;
  const float* xb = x + (size_t)b * Dm * Ln;
  for (int i = tid; i < Dm * 16; i += 256) {
    int d = i >> 4, l4 = (i & 15) << 2;
    float4 v = *(const float4*)&xb[d * Ln + l0 + l4];
    tile[d * 65 + l4]     = v.x; tile[d * 65 + l4 + 1] = v.y;
    tile[d * 65 + l4 + 2] = v.z; tile[d * 65 + l4 + 3] = v.w;
  }
  __syncthreads();
  int lane = tid & 63, wv = tid >> 6;
  float ga0 = g1[lane], ga1 = g1[lane + 64], ga2 = g1[lane + 128];
  float bb0 = b1[lane], bb1 = b1[lane + 64], bb2 = b1[lane + 128];
  float gc0 = g2[lane], gc1 = g2[lane + 64], gc2 = g2[lane + 128];
  float bc0 = b2[lane], bc1 = b2[lane + 64], bc2 = b2[lane + 128];
  for (int li = wv; li < 64; li += 4) {
    float v0 = tile[lane * 65 + li], v1 = tile[(lane + 64) * 65 + li], v2 = tile[(lane + 128) * 65 + li];
    float s  = wave_sum(v0 + v1 + v2);
    float sq = wave_sum(v0 * v0 + v1 * v1 + v2 * v2);
    float m = s * (1.f / 192.f);
    float inv = rsqrtf(sq * (1.f / 192.f) - m * m + 1e-5f);
    float y0 = (v0 - m) * inv * ga0 + bb0;
    float y1 = (v1 - m) * inv * ga1 + bb1;
    float y2 = (v2 - m) * inv * ga2 + bb2;
    float s2  = wave_sum(y0 + y1 + y2);
    float sq2 = wave_sum(y0 * y0 + y1 * y1 + y2 * y2);
    float m2 = s2 * (1.f / 192.f);
    float inv2 = rsqrtf(sq2 * (1.f / 192.f) - m2 * m2 + 1e-5f);
    size_t base = ((size_t)b * Ln + l0 + li) * Dm;
    xln1b[base + lane]       = f2b(y0);
    xln1b[base + lane + 64]  = f2b(y1);
    xln1b[base + lane + 128] = f2b(y2);
    xnb[base + lane]       = f2b((y0 - m2) * inv2 * gc0 + bc0);
    xnb[base + lane + 64]  = f2b((y1 - m2) * inv2 * gc1 + bc1);
    xnb[base + lane + 128] = f2b((y2 - m2) * inv2 * gc2 + bc2);
  }
}

// ---- K2: weights -> bf16 (dt|B|C|xp cat, out_w, w1, w2) --------------------
__global__ __launch_bounds__(256) void k_wconv(
    const float* __restrict__ dt_w, const float* __restrict__ B_w,
    const float* __restrict__ C_w, const float* __restrict__ xp_w,
    const float* __restrict__ out_w, const float* __restrict__ w1,
    const float* __restrict__ w2, short* __restrict__ wb) {
  int i = blockIdx.x * 256 + threadIdx.x;  // 89088 float4 groups total
  const float4* src;
  if (i < 3072)       src = (const float4*)dt_w + i;
  else if (i < 6144)  src = (const float4*)B_w + (i - 3072);
  else if (i < 9216)  src = (const float4*)C_w + (i - 6144);
  else if (i < 12288) src = (const float4*)xp_w + (i - 9216);
  else if (i < 15360) src = (const float4*)out_w + (i - 12288);
  else if (i < 52224) src = (const float4*)w1 + (i - 15360);
  else                src = (const float4*)w2 + (i - 52224);
  float4 v = *src;
  int o = i * 4;
  wb[o]     = f2b(v.x); wb[o + 1] = f2b(v.y);
  wb[o + 2] = f2b(v.z); wb[o + 3] = f2b(v.w);
}

// ---- K3: MFMA proj GEMM [32768x256, K=192] + in-register SSM epilogue ------
__global__ __launch_bounds__(256) void k_proj(
    const short* __restrict__ xnb, const short* __restrict__ wcat,
    const float* __restrict__ dt_b, const float* __restrict__ xp_b,
    const float* __restrict__ A_log, float* __restrict__ abc) {
  __shared__ __align__(16) short As[128 * 72];
  __shared__ __align__(16) short Bs[256 * 72];
  int m0 = blockIdx.x * 128, tid = threadIdx.x;
  int lane = tid & 63, l16 = lane & 15, quad = lane >> 4, w = tid >> 6;
  f32x4 acc[2][16] = {};
  for (int kt = 0; kt < 3; kt++) {
    int kb = kt * 64;
    for (int i = tid; i < 1024; i += 256) {
      int row = i >> 3, c8 = (i & 7) * 8;
      *(float4*)&As[row * 72 + c8] = *(const float4*)&xnb[(size_t)(m0 + row) * 192 + kb + c8];
    }
    for (int i = tid; i < 2048; i += 256) {
      int row = i >> 3, c8 = (i & 7) * 8;
      *(float4*)&Bs[row * 72 + c8] = *(const float4*)&wcat[(size_t)row * 192 + kb + c8];
    }
    __syncthreads();
#pragma unroll
    for (int ks = 0; ks < 2; ks++) {
      int ko = ks * 32 + quad * 8;
      bf16x8 a0 = *(const bf16x8*)&As[(w * 32 + l16) * 72 + ko];
      bf16x8 a1 = *(const bf16x8*)&As[(w * 32 + 16 + l16) * 72 + ko];
#pragma unroll
      for (int nh = 0; nh < 2; nh++) {
        bf16x8 bfr[8];
#pragma unroll
        for (int j = 0; j < 8; j++) bfr[j] = *(const bf16x8*)&Bs[((nh * 8 + j) * 16 + l16) * 72 + ko];
#pragma unroll
        for (int j = 0; j < 8; j++) {
          acc[0][nh * 8 + j] = __builtin_amdgcn_mfma_f32_16x16x32_bf16(a0, bfr[j], acc[0][nh * 8 + j], 0, 0, 0);
          acc[1][nh * 8 + j] = __builtin_amdgcn_mfma_f32_16x16x32_bf16(a1, bfr[j], acc[1][nh * 8 + j], 0, 0, 0);
        }
      }
    }
    __syncthreads();
  }
  float Av[4], dtb[4], xpb[4];
#pragma unroll
  for (int ni = 0; ni < 4; ni++) {
    int s = ni * 16 + l16;
    Av[ni] = -expf(A_log[s]); dtb[ni] = dt_b[s]; xpb[ni] = xp_b[s];
  }
#pragma unroll
  for (int mi = 0; mi < 2; mi++)
#pragma unroll
    for (int r = 0; r < 4; r++) {
      int m = m0 + w * 32 + mi * 16 + quad * 4 + r;
      float* orow = abc + (size_t)m * 192;
#pragma unroll
      for (int ni = 0; ni < 4; ni++) {
        int s = ni * 16 + l16;
        float z = acc[mi][ni][r] + dtb[ni];
        float sp = (z > 20.f) ? z : log1pf(expf(z));
        float delta = sp * 0.01f + 0.0001f;
        float bt  = acc[mi][ni + 4][r];
        float ct  = acc[mi][ni + 8][r];
        float xpv = acc[mi][ni + 12][r] + xpb[ni];
        float dA = fminf(fmaxf(delta * Av[ni], -10.f), -0.0001f);
        float Ae = fminf(fmaxf(expf(dA), 0.001f), 0.999f) + 1e-10f;
        orow[s]       = Ae;
        orow[64 + s]  = delta * bt * xpv;
        orow[128 + s] = ct;
      }
    }
}

// ---- K4: scan phase 1 (64-step chunk summaries) ----------------------------
__global__ __launch_bounds__(64) void k_scan1(const float* __restrict__ abc, float* __restrict__ sums) {
  int c = blockIdx.x, b = blockIdx.y, s = threadIdx.x;
  const float* p = abc + ((size_t)b * Ln + c * 64) * 192;
  float prodA = 1.f, h = 0.f;
  int t = 0;
  if (c == 0) { prodA = p[s]; h = p[64 + s]; t = 1; }
#pragma unroll 4
  for (; t < 64; t++) {
    float a = p[t * 192 + s], bx = p[t * 192 + 64 + s];
    h = a * (h + bx);
    prodA *= a;
  }
  int ci = b * 64 + c;
  sums[(ci * 2 + 0) * 64 + s] = prodA;
  sums[(ci * 2 + 1) * 64 + s] = h;
}

// ---- K5: scan phase 2 (carry chain over 64 chunks), one block per batch ----
__global__ __launch_bounds__(64) void k_scan2(const float* __restrict__ sums, float* __restrict__ carries) {
  int b = blockIdx.x, s = threadIdx.x;
  float cur = 0.f;
  for (int c = 0; c < 64; c++) {
    int ci = b * 64 + c;
    carries[ci * 64 + s] = cur;
    cur = sums[(ci * 2 + 0) * 64 + s] * cur + sums[(ci * 2 + 1) * 64 + s];
  }
}

// ---- K6: scan phase 3 (replay, y = C*h -> bf16) ----------------------------
__global__ __launch_bounds__(64) void k_scan3(const float* __restrict__ abc, const float* __restrict__ carries,
                                              short* __restrict__ y) {
  int c = blockIdx.x, b = blockIdx.y, s = threadIdx.x;
  size_t r0 = (size_t)b * Ln + c * 64;
  const float* p = abc + r0 * 192;
  short* yo = y + r0 * 64;
  float h = carries[(b * 64 + c) * 64 + s];
  int t = 0;
  if (c == 0) { h = p[64 + s]; yo[s] = f2b(p[128 + s] * h); t = 1; }
#pragma unroll 4
  for (; t < 64; t++) {
    float a = p[t * 192 + s], bx = p[t * 192 + 64 + s], ct = p[t * 192 + 128 + s];
    h = a * (h + bx);
    yo[t * 64 + s] = f2b(ct * h);
  }
}

// ---- K7: MFMA out-proj (swapped): sout[d][l] = out_w @ y^T + b (+D skip) ---
__global__ __launch_bounds__(256) void k_out(
    const short* __restrict__ y, const short* __restrict__ owb, const float* __restrict__ out_b,
    const float* __restrict__ Dp, const short* __restrict__ xln1b, float* __restrict__ sout) {
  __shared__ __align__(16) short As[192 * 72];
  __shared__ __align__(16) short Bs[128 * 72];
  int l0g = blockIdx.x * 128, tid = threadIdx.x;
  int lane = tid & 63, l16 = lane & 15, quad = lane >> 4;
  int wm = (tid >> 6) >> 1, wn = (tid >> 6) & 1;
  f32x4 acc[6][4] = {};
  for (int i = tid; i < 1536; i += 256) {
    int row = i >> 3, c8 = (i & 7) * 8;
    *(float4*)&As[row * 72 + c8] = *(const float4*)&owb[row * 64 + c8];
  }
  for (int i = tid; i < 1024; i += 256) {
    int row = i >> 3, c8 = (i & 7) * 8;
    *(float4*)&Bs[row * 72 + c8] = *(const float4*)&y[(size_t)(l0g + row) * 64 + c8];
  }
  __syncthreads();
#pragma unroll
  for (int ks = 0; ks < 2; ks++) {
    int ko = ks * 32 + quad * 8;
    bf16x8 a[6], b[4];
#pragma unroll
    for (int mi = 0; mi < 6; mi++) a[mi] = *(const bf16x8*)&As[(wm * 96 + mi * 16 + l16) * 72 + ko];
#pragma unroll
    for (int ni = 0; ni < 4; ni++) b[ni] = *(const bf16x8*)&Bs[(wn * 64 + ni * 16 + l16) * 72 + ko];
#pragma unroll
    for (int mi = 0; mi < 6; mi++)
#pragma unroll
      for (int ni = 0; ni < 4; ni++)
        acc[mi][ni] = __builtin_amdgcn_mfma_f32_16x16x32_bf16(a[mi], b[ni], acc[mi][ni], 0, 0, 0);
  }
  int bb = l0g >> 12;
#pragma unroll
  for (int mi = 0; mi < 6; mi++)
#pragma unroll
    for (int r = 0; r < 4; r++) {
      int d = wm * 96 + mi * 16 + quad * 4 + r;
      float ob = out_b[d];
      float dc = fminf(fmaxf(Dp[d], -2.f), 2.f);
#pragma unroll
      for (int ni = 0; ni < 4; ni++) {
        int l = l0g + wn * 64 + ni * 16 + l16;
        float v = acc[mi][ni][r] + ob;
        if (dc != 0.f) v += dc * b2f(xln1b[(size_t)l * 192 + d]);
        sout[((size_t)bb * Dm + d) * Ln + (l & 4095)] = v;
      }
    }
}

// ---- K8: depthwise conv 3x3 + BN + residual combine -> xr (NCHW) -----------
__global__ __launch_bounds__(256) void k_conv(
    const float* __restrict__ x, const float* __restrict__ dw,
    const float* __restrict__ bn_g, const float* __restrict__ bn_b,
    const float* __restrict__ bn_rm, const float* __restrict__ bn_rv,
    const float* __restrict__ sout, const float* __restrict__ a_loc,
    const float* __restrict__ a_ssm, float* __restrict__ xr) {
  __shared__ __align__(16) float xs[64 * 64];
  int d = blockIdx.x, b = blockIdx.y, tid = threadIdx.x;
  const float* xp = x + ((size_t)b * Dm + d) * Ln;
  for (int i = tid; i < 1024; i += 256) ((float4*)xs)[i] = ((const float4*)xp)[i];
  __syncthreads();
  float w[9];
#pragma unroll
  for (int k = 0; k < 9; k++) w[k] = dw[d * 9 + k];
  float scale = bn_g[d] * rsqrtf(bn_rv[d] + 1e-5f);
  float rm = bn_rm[d], bb = bn_b[d];
  float al = a_loc[0], as_ = a_ssm[0];
  const float* sp = sout + ((size_t)b * Dm + d) * Ln;
  float* xo = xr + ((size_t)b * Dm + d) * Ln;
  for (int i = tid; i < 4096; i += 256) {
    int h = i >> 6, wc = i & 63;
    float acc = 0.f;
#pragma unroll
    for (int kh = 0; kh < 3; kh++) {
      int hh = h + kh - 1;
      if (hh < 0 || hh >= 64) continue;
#pragma unroll
      for (int kw = 0; kw < 3; kw++) {
        int ww2 = wc + kw - 1;
        if (ww2 < 0 || ww2 >= 64) continue;
        acc += xs[hh * 64 + ww2] * w[kh * 3 + kw];
      }
    }
    float xl = (acc - rm) * scale + bb;
    xo[i] = xs[i] + al * xl + as_ * sp[i];
  }
}

// ---- K9: ln2 -> bf16 xn2 [B*L, 192] row-major ------------------------------
__global__ __launch_bounds__(256) void k_ln2(
    const float* __restrict__ xr, const float* __restrict__ g, const float* __restrict__ bb,
    short* __restrict__ xn2) {
  __shared__ __align__(16) float tile[Dm * 65];
  int b = blockIdx.y, l0 = blockIdx.x * 64, tid = threadIdx.x;
  const float* xb = xr + (size_t)b * Dm * Ln;
  for (int i = tid; i < Dm * 16; i += 256) {
    int d = i >> 4, l4 = (i & 15) << 2;
    float4 v = *(const float4*)&xb[d * Ln + l0 + l4];
    tile[d * 65 + l4]     = v.x; tile[d * 65 + l4 + 1] = v.y;
    tile[d * 65 + l4 + 2] = v.z; tile[d * 65 + l4 + 3] = v.w;
  }
  __syncthreads();
  int lane = tid & 63, wv = tid >> 6;
  float g0 = g[lane], g1v = g[lane + 64], g2v = g[lane + 128];
  float b0 = bb[lane], b1v = bb[lane + 64], b2v = bb[lane + 128];
  for (int li = wv; li < 64; li += 4) {
    float v0 = tile[lane * 65 + li], v1 = tile[(lane + 64) * 65 + li], v2 = tile[(lane + 128) * 65 + li];
    float s  = wave_sum(v0 + v1 + v2);
    float sq = wave_sum(v0 * v0 + v1 * v1 + v2 * v2);
    float m = s * (1.f / 192.f);
    float inv = rsqrtf(sq * (1.f / 192.f) - m * m + 1e-5f);
    size_t base = ((size_t)b * Ln + l0 + li) * Dm;
    xn2[base + lane]       = f2b((v0 - m) * inv * g0 + b0);
    xn2[base + lane + 64]  = f2b((v1 - m) * inv * g1v + b1v);
    xn2[base + lane + 128] = f2b((v2 - m) * inv * g2v + b2v);
  }
}

// ---- K10: MFMA GEMM1: hid = gelu(xn2 @ w1^T + b1), LDS-staged coalesced out
__global__ __launch_bounds__(256) void k_gemm1(
    const short* __restrict__ xn2, const short* __restrict__ w1b,
    const float* __restrict__ b1h, short* __restrict__ hid) {
  __shared__ __align__(16) short smem[2 * 128 * 88];  // As | Bs; reused as C-stage
  short* As = smem;
  short* Bs = smem + 128 * 88;
  int m0 = blockIdx.x * 128, n0 = blockIdx.y * 128, tid = threadIdx.x;
  int lane = tid & 63, l16 = lane & 15, quad = lane >> 4;
  int wm = (tid >> 6) >> 1, wn = (tid >> 6) & 1;
  f32x4 acc[4][4] = {};
  for (int kt = 0; kt < 3; kt++) {
    int kb = kt * 64;
    for (int i = tid; i < 1024; i += 256) {
      int row = i >> 3, c8 = (i & 7) * 8;
      *(float4*)&As[row * 88 + c8] = *(const float4*)&xn2[(size_t)(m0 + row) * 192 + kb + c8];
      *(float4*)&Bs[row * 88 + c8] = *(const float4*)&w1b[(size_t)(n0 + row) * 192 + kb + c8];
    }
    __syncthreads();
#pragma unroll
    for (int ks = 0; ks < 2; ks++) {
      int ko = ks * 32 + quad * 8;
      bf16x8 a[4], b[4];
#pragma unroll
      for (int mi = 0; mi < 4; mi++) a[mi] = *(const bf16x8*)&As[(wm * 64 + mi * 16 + l16) * 88 + ko];
#pragma unroll
      for (int ni = 0; ni < 4; ni++) b[ni] = *(const bf16x8*)&Bs[(wn * 64 + ni * 16 + l16) * 88 + ko];
#pragma unroll
      for (int mi = 0; mi < 4; mi++)
#pragma unroll
        for (int ni = 0; ni < 4; ni++)
          acc[mi][ni] = __builtin_amdgcn_mfma_f32_16x16x32_bf16(a[mi], b[ni], acc[mi][ni], 0, 0, 0);
    }
    __syncthreads();
  }
  // Epilogue: bias+gelu -> bf16 C-stage in LDS [128 m][136 pad], coalesced store
  short* Cs = smem;
  float bias4[4];
#pragma unroll
  for (int ni = 0; ni < 4; ni++) bias4[ni] = b1h[n0 + wn * 64 + ni * 16 + l16];
#pragma unroll
  for (int mi = 0; mi < 4; mi++)
#pragma unroll
    for (int ni = 0; ni < 4; ni++) {
      int n = wn * 64 + ni * 16 + l16;
#pragma unroll
      for (int r = 0; r < 4; r++) {
        int m = wm * 64 + mi * 16 + quad * 4 + r;
        float v = acc[mi][ni][r] + bias4[ni];
        float g = 0.5f * v * (1.f + erff(v * 0.70710678118f));
        Cs[m * 136 + n] = f2b(g);
      }
    }
  __syncthreads();
  for (int i = tid; i < 2048; i += 256) {
    int m = i >> 4, ch = i & 15;
    *(float4*)&hid[(size_t)(m0 + m) * 768 + n0 + ch * 8] = *(const float4*)&Cs[m * 136 + ch * 8];
  }
}

// ---- K11: MFMA GEMM2 (swapped): D[d][l] = w2 @ hid^T; out = xr + a*(D+b) ----
// l-tile = 128 to halve w2 restaging.
__global__ __launch_bounds__(256) void k_gemm2(
    const short* __restrict__ hid, const short* __restrict__ w2b,
    const float* __restrict__ b2o, const float* __restrict__ xr,
    const float* __restrict__ am, float* __restrict__ out) {
  __shared__ __align__(16) short Wt[192 * 88];
  __shared__ __align__(16) short Ht[128 * 88];
  int l0g = blockIdx.x * 128, tid = threadIdx.x;
  int lane = tid & 63, l16 = lane & 15, quad = lane >> 4;
  int wm = (tid >> 6) >> 1, wn = (tid >> 6) & 1;  // wm: d-half(96), wn: l-half(64)
  f32x4 acc[6][4] = {};
  for (int kt = 0; kt < 12; kt++) {
    int kb = kt * 64;
    for (int i = tid; i < 1536; i += 256) {
      int row = i >> 3, c8 = (i & 7) * 8;
      *(float4*)&Wt[row * 88 + c8] = *(const float4*)&w2b[(size_t)row * 768 + kb + c8];
    }
    for (int i = tid; i < 1024; i += 256) {
      int row = i >> 3, c8 = (i & 7) * 8;
      *(float4*)&Ht[row * 88 + c8] = *(const float4*)&hid[(size_t)(l0g + row) * 768 + kb + c8];
    }
    __syncthreads();
#pragma unroll
    for (int ks = 0; ks < 2; ks++) {
      int ko = ks * 32 + quad * 8;
      bf16x8 a[6], b[4];
#pragma unroll
      for (int mi = 0; mi < 6; mi++) a[mi] = *(const bf16x8*)&Wt[(wm * 96 + mi * 16 + l16) * 88 + ko];
#pragma unroll
      for (int ni = 0; ni < 4; ni++) b[ni] = *(const bf16x8*)&Ht[(wn * 64 + ni * 16 + l16) * 88 + ko];
#pragma unroll
      for (int mi = 0; mi < 6; mi++)
#pragma unroll
        for (int ni = 0; ni < 4; ni++)
          acc[mi][ni] = __builtin_amdgcn_mfma_f32_16x16x32_bf16(a[mi], b[ni], acc[mi][ni], 0, 0, 0);
    }
    __syncthreads();
  }
  float alpha = am[0];
#pragma unroll
  for (int mi = 0; mi < 6; mi++)
#pragma unroll
    for (int r = 0; r < 4; r++) {
      int d = wm * 96 + mi * 16 + quad * 4 + r;
      float bias = b2o[d];
#pragma unroll
      for (int ni = 0; ni < 4; ni++) {
        int lg = l0g + wn * 64 + ni * 16 + l16;
        size_t idx = ((size_t)(lg >> 12) * Dm + d) * Ln + (lg & 4095);
        out[idx] = xr[idx] + alpha * (acc[mi][ni][r] + bias);
      }
    }
}

extern "C" void kernel_launch(void* const* d_in, const int* in_sizes, int n_in,
                              void* d_out, int out_size, void* d_ws, size_t ws_size,
                              hipStream_t stream) {
  (void)in_sizes; (void)n_in; (void)out_size; (void)ws_size;
  const float* x     = (const float*)d_in[0];
  const float* ln1_g = (const float*)d_in[1];
  const float* ln1_b = (const float*)d_in[2];
  const float* ln2_g = (const float*)d_in[3];
  const float* ln2_b = (const float*)d_in[4];
  const float* dw_w  = (const float*)d_in[5];
  const float* bn_g  = (const float*)d_in[6];
  const float* bn_b  = (const float*)d_in[7];
  const float* bn_rm = (const float*)d_in[8];
  const float* bn_rv = (const float*)d_in[9];
  const float* ssm_g = (const float*)d_in[10];
  const float* ssm_b = (const float*)d_in[11];
  const float* xp_w  = (const float*)d_in[12];
  const float* xp_b  = (const float*)d_in[13];
  const float* dt_w  = (const float*)d_in[14];
  const float* dt_b  = (const float*)d_in[15];
  const float* A_log = (const float*)d_in[16];
  const float* B_w   = (const float*)d_in[17];
  const float* C_w   = (const float*)d_in[18];
  const float* Dp    = (const float*)d_in[19];
  const float* out_w = (const float*)d_in[20];
  const float* out_b = (const float*)d_in[21];
  const float* w1    = (const float*)d_in[22];
  const float* b1    = (const float*)d_in[23];
  const float* w2    = (const float*)d_in[24];
  const float* b2    = (const float*)d_in[25];
  const float* a_loc = (const float*)d_in[26];
  const float* a_ssm = (const float*)d_in[27];
  const float* a_mlp = (const float*)d_in[28];

  float* ws = (float*)d_ws;
  short* xnb   = (short*)ws;
  short* xln1b = (short*)(ws + 3145728);
  float* abc   = ws + 6291456;
  short* yB    = (short*)(ws + 12582912);
  float* sums  = ws + 13631488;
  float* carr  = ws + 13697024;
  float* sout  = ws + 13729792;
  float* xr    = ws + 20021248;
  short* wb    = (short*)(ws + 26312704);
  short* wcatb = wb;            // [256,192]
  short* owb   = wb + 49152;    // [192,64]
  short* w1b   = wb + 61440;    // [768,192]
  short* w2b   = wb + 208896;   // [192,768]
  short* xn2   = (short*)ws;               // aliases xnb (dead after k_proj)
  short* hid   = (short*)(ws + 6291456);   // aliases abc..sout head (dead by then)
  float* out   = (float*)d_out;

  k_ln   <<<dim3(64, 8),  256, 0, stream>>>(x, ln1_g, ln1_b, ssm_g, ssm_b, xnb, xln1b);
  k_wconv<<<dim3(348),    256, 0, stream>>>(dt_w, B_w, C_w, xp_w, out_w, w1, w2, wb);
  k_proj <<<dim3(256),    256, 0, stream>>>(xnb, wcatb, dt_b, xp_b, A_log, abc);
  k_scan1<<<dim3(64, 8),   64, 0, stream>>>(abc, sums);
  k_scan2<<<dim3(8),       64, 0, stream>>>(sums, carr);
  k_scan3<<<dim3(64, 8),   64, 0, stream>>>(abc, carr, yB);
  k_out  <<<dim3(256),    256, 0, stream>>>(yB, owb, out_b, Dp, xln1b, sout);
  k_conv <<<dim3(192, 8), 256, 0, stream>>>(x, dw_w, bn_g, bn_b, bn_rm, bn_rv, sout, a_loc, a_ssm, xr);
  k_ln2  <<<dim3(64, 8),  256, 0, stream>>>(xr, ln2_g, ln2_b, xn2);
  k_gemm1<<<dim3(256, 6), 256, 0, stream>>>(xn2, w1b, b1, hid);
  k_gemm2<<<dim3(256),    256, 0, stream>>>(hid, w2b, b2, xr, a_mlp, out);
}

// Round 5
// 308.861 us; speedup vs baseline: 3.9304x; 1.0460x over previous
//
#include <hip/hip_runtime.h>
#include <hip/hip_bf16.h>
#include <math.h>

// MambaBlock fused pipeline v5: gemm2 split-d grid (512 blocks, 4/CU).
// ws layout (floats): see v3 comments — unchanged.

#define DEV static __device__ __forceinline__

constexpr int Bn = 8, Dm = 192, Ln = 4096, Sn = 64, Hd = 768;

typedef __attribute__((ext_vector_type(8))) short bf16x8;
typedef __attribute__((ext_vector_type(4))) float f32x4;

DEV float wave_sum(float v) {
#pragma unroll
  for (int off = 1; off < 64; off <<= 1) v += __shfl_xor(v, off);
  return v;
}

DEV short f2b(float x) {
  __hip_bfloat16 h = __float2bfloat16(x);
  return *(short*)&h;
}

DEV float b2f(short x) {
  __hip_bfloat16 h = *(__hip_bfloat16*)&x;
  return __bfloat162float(h);
}

// ---- K1: transpose + ln1 + ssm_ln -> bf16 xn, bf16 xln1 --------------------
__global__ __launch_bounds__(256) void k_ln(
    const float* __restrict__ x, const float* __restrict__ g1, const float* __restrict__ b1,
    const float* __restrict__ g2, const float* __restrict__ b2,
    short* __restrict__ xnb, short* __restrict__ xln1b) {
  __shared__ __align__(16) float tile[Dm * 65];
  int b = blockIdx.y, l0 = blockIdx.x * 64, tid = threadIdx.x;
  const float* xb = x + (size_t)b * Dm * Ln;
  for (int i = tid; i < Dm * 16; i += 256) {
    int d = i >> 4, l4 = (i & 15) << 2;
    float4 v = *(const float4*)&xb[d * Ln + l0 + l4];
    tile[d * 65 + l4]     = v.x; tile[d * 65 + l4 + 1] = v.y;
    tile[d * 65 + l4 + 2] = v.z; tile[d * 65 + l4 + 3] = v.w;
  }
  __syncthreads();
  int lane = tid & 63, wv = tid >> 6;
  float ga0 = g1[lane], ga1 = g1[lane + 64], ga2 = g1[lane + 128];
  float bb0 = b1[lane], bb1 = b1[lane + 64], bb2 = b1[lane + 128];
  float gc0 = g2[lane], gc1 = g2[lane + 64], gc2 = g2[lane + 128];
  float bc0 = b2[lane], bc1 = b2[lane + 64], bc2 = b2[lane + 128];
  for (int li = wv; li < 64; li += 4) {
    float v0 = tile[lane * 65 + li], v1 = tile[(lane + 64) * 65 + li], v2 = tile[(lane + 128) * 65 + li];
    float s  = wave_sum(v0 + v1 + v2);
    float sq = wave_sum(v0 * v0 + v1 * v1 + v2 * v2);
    float m = s * (1.f / 192.f);
    float inv = rsqrtf(sq * (1.f / 192.f) - m * m + 1e-5f);
    float y0 = (v0 - m) * inv * ga0 + bb0;
    float y1 = (v1 - m) * inv * ga1 + bb1;
    float y2 = (v2 - m) * inv * ga2 + bb2;
    float s2  = wave_sum(y0 + y1 + y2);
    float sq2 = wave_sum(y0 * y0 + y1 * y1 + y2 * y2);
    float m2 = s2 * (1.f / 192.f);
    float inv2 = rsqrtf(sq2 * (1.f / 192.f) - m2 * m2 + 1e-5f);
    size_t base = ((size_t)b * Ln + l0 + li) * Dm;
    xln1b[base + lane]       = f2b(y0);
    xln1b[base + lane + 64]  = f2b(y1);
    xln1b[base + lane + 128] = f2b(y2);
    xnb[base + lane]       = f2b((y0 - m2) * inv2 * gc0 + bc0);
    xnb[base + lane + 64]  = f2b((y1 - m2) * inv2 * gc1 + bc1);
    xnb[base + lane + 128] = f2b((y2 - m2) * inv2 * gc2 + bc2);
  }
}

// ---- K2: weights -> bf16 (dt|B|C|xp cat, out_w, w1, w2) --------------------
__global__ __launch_bounds__(256) void k_wconv(
    const float* __restrict__ dt_w, const float* __restrict__ B_w,
    const float* __restrict__ C_w, const float* __restrict__ xp_w,
    const float* __restrict__ out_w, const float* __restrict__ w1,
    const float* __restrict__ w2, short* __restrict__ wb) {
  int i = blockIdx.x * 256 + threadIdx.x;  // 89088 float4 groups total
  const float4* src;
  if (i < 3072)       src = (const float4*)dt_w + i;
  else if (i < 6144)  src = (const float4*)B_w + (i - 3072);
  else if (i < 9216)  src = (const float4*)C_w + (i - 6144);
  else if (i < 12288) src = (const float4*)xp_w + (i - 9216);
  else if (i < 15360) src = (const float4*)out_w + (i - 12288);
  else if (i < 52224) src = (const float4*)w1 + (i - 15360);
  else                src = (const float4*)w2 + (i - 52224);
  float4 v = *src;
  int o = i * 4;
  wb[o]     = f2b(v.x); wb[o + 1] = f2b(v.y);
  wb[o + 2] = f2b(v.z); wb[o + 3] = f2b(v.w);
}

// ---- K3: MFMA proj GEMM [32768x256, K=192] + in-register SSM epilogue ------
__global__ __launch_bounds__(256) void k_proj(
    const short* __restrict__ xnb, const short* __restrict__ wcat,
    const float* __restrict__ dt_b, const float* __restrict__ xp_b,
    const float* __restrict__ A_log, float* __restrict__ abc) {
  __shared__ __align__(16) short As[128 * 72];
  __shared__ __align__(16) short Bs[256 * 72];
  int m0 = blockIdx.x * 128, tid = threadIdx.x;
  int lane = tid & 63, l16 = lane & 15, quad = lane >> 4, w = tid >> 6;
  f32x4 acc[2][16] = {};
  for (int kt = 0; kt < 3; kt++) {
    int kb = kt * 64;
    for (int i = tid; i < 1024; i += 256) {
      int row = i >> 3, c8 = (i & 7) * 8;
      *(float4*)&As[row * 72 + c8] = *(const float4*)&xnb[(size_t)(m0 + row) * 192 + kb + c8];
    }
    for (int i = tid; i < 2048; i += 256) {
      int row = i >> 3, c8 = (i & 7) * 8;
      *(float4*)&Bs[row * 72 + c8] = *(const float4*)&wcat[(size_t)row * 192 + kb + c8];
    }
    __syncthreads();
#pragma unroll
    for (int ks = 0; ks < 2; ks++) {
      int ko = ks * 32 + quad * 8;
      bf16x8 a0 = *(const bf16x8*)&As[(w * 32 + l16) * 72 + ko];
      bf16x8 a1 = *(const bf16x8*)&As[(w * 32 + 16 + l16) * 72 + ko];
#pragma unroll
      for (int nh = 0; nh < 2; nh++) {
        bf16x8 bfr[8];
#pragma unroll
        for (int j = 0; j < 8; j++) bfr[j] = *(const bf16x8*)&Bs[((nh * 8 + j) * 16 + l16) * 72 + ko];
#pragma unroll
        for (int j = 0; j < 8; j++) {
          acc[0][nh * 8 + j] = __builtin_amdgcn_mfma_f32_16x16x32_bf16(a0, bfr[j], acc[0][nh * 8 + j], 0, 0, 0);
          acc[1][nh * 8 + j] = __builtin_amdgcn_mfma_f32_16x16x32_bf16(a1, bfr[j], acc[1][nh * 8 + j], 0, 0, 0);
        }
      }
    }
    __syncthreads();
  }
  float Av[4], dtb[4], xpb[4];
#pragma unroll
  for (int ni = 0; ni < 4; ni++) {
    int s = ni * 16 + l16;
    Av[ni] = -expf(A_log[s]); dtb[ni] = dt_b[s]; xpb[ni] = xp_b[s];
  }
#pragma unroll
  for (int mi = 0; mi < 2; mi++)
#pragma unroll
    for (int r = 0; r < 4; r++) {
      int m = m0 + w * 32 + mi * 16 + quad * 4 + r;
      float* orow = abc + (size_t)m * 192;
#pragma unroll
      for (int ni = 0; ni < 4; ni++) {
        int s = ni * 16 + l16;
        float z = acc[mi][ni][r] + dtb[ni];
        float sp = (z > 20.f) ? z : log1pf(expf(z));
        float delta = sp * 0.01f + 0.0001f;
        float bt  = acc[mi][ni + 4][r];
        float ct  = acc[mi][ni + 8][r];
        float xpv = acc[mi][ni + 12][r] + xpb[ni];
        float dA = fminf(fmaxf(delta * Av[ni], -10.f), -0.0001f);
        float Ae = fminf(fmaxf(expf(dA), 0.001f), 0.999f) + 1e-10f;
        orow[s]       = Ae;
        orow[64 + s]  = delta * bt * xpv;
        orow[128 + s] = ct;
      }
    }
}

// ---- K4: scan phase 1 (64-step chunk summaries) ----------------------------
__global__ __launch_bounds__(64) void k_scan1(const float* __restrict__ abc, float* __restrict__ sums) {
  int c = blockIdx.x, b = blockIdx.y, s = threadIdx.x;
  const float* p = abc + ((size_t)b * Ln + c * 64) * 192;
  float prodA = 1.f, h = 0.f;
  int t = 0;
  if (c == 0) { prodA = p[s]; h = p[64 + s]; t = 1; }
#pragma unroll 4
  for (; t < 64; t++) {
    float a = p[t * 192 + s], bx = p[t * 192 + 64 + s];
    h = a * (h + bx);
    prodA *= a;
  }
  int ci = b * 64 + c;
  sums[(ci * 2 + 0) * 64 + s] = prodA;
  sums[(ci * 2 + 1) * 64 + s] = h;
}

// ---- K5: scan phase 2 (carry chain over 64 chunks), one block per batch ----
__global__ __launch_bounds__(64) void k_scan2(const float* __restrict__ sums, float* __restrict__ carries) {
  int b = blockIdx.x, s = threadIdx.x;
  float cur = 0.f;
  for (int c = 0; c < 64; c++) {
    int ci = b * 64 + c;
    carries[ci * 64 + s] = cur;
    cur = sums[(ci * 2 + 0) * 64 + s] * cur + sums[(ci * 2 + 1) * 64 + s];
  }
}

// ---- K6: scan phase 3 (replay, y = C*h -> bf16) ----------------------------
__global__ __launch_bounds__(64) void k_scan3(const float* __restrict__ abc, const float* __restrict__ carries,
                                              short* __restrict__ y) {
  int c = blockIdx.x, b = blockIdx.y, s = threadIdx.x;
  size_t r0 = (size_t)b * Ln + c * 64;
  const float* p = abc + r0 * 192;
  short* yo = y + r0 * 64;
  float h = carries[(b * 64 + c) * 64 + s];
  int t = 0;
  if (c == 0) { h = p[64 + s]; yo[s] = f2b(p[128 + s] * h); t = 1; }
#pragma unroll 4
  for (; t < 64; t++) {
    float a = p[t * 192 + s], bx = p[t * 192 + 64 + s], ct = p[t * 192 + 128 + s];
    h = a * (h + bx);
    yo[t * 64 + s] = f2b(ct * h);
  }
}

// ---- K7: MFMA out-proj (swapped): sout[d][l] = out_w @ y^T + b (+D skip) ---
__global__ __launch_bounds__(256) void k_out(
    const short* __restrict__ y, const short* __restrict__ owb, const float* __restrict__ out_b,
    const float* __restrict__ Dp, const short* __restrict__ xln1b, float* __restrict__ sout) {
  __shared__ __align__(16) short As[192 * 72];
  __shared__ __align__(16) short Bs[128 * 72];
  int l0g = blockIdx.x * 128, tid = threadIdx.x;
  int lane = tid & 63, l16 = lane & 15, quad = lane >> 4;
  int wm = (tid >> 6) >> 1, wn = (tid >> 6) & 1;
  f32x4 acc[6][4] = {};
  for (int i = tid; i < 1536; i += 256) {
    int row = i >> 3, c8 = (i & 7) * 8;
    *(float4*)&As[row * 72 + c8] = *(const float4*)&owb[row * 64 + c8];
  }
  for (int i = tid; i < 1024; i += 256) {
    int row = i >> 3, c8 = (i & 7) * 8;
    *(float4*)&Bs[row * 72 + c8] = *(const float4*)&y[(size_t)(l0g + row) * 64 + c8];
  }
  __syncthreads();
#pragma unroll
  for (int ks = 0; ks < 2; ks++) {
    int ko = ks * 32 + quad * 8;
    bf16x8 a[6], b[4];
#pragma unroll
    for (int mi = 0; mi < 6; mi++) a[mi] = *(const bf16x8*)&As[(wm * 96 + mi * 16 + l16) * 72 + ko];
#pragma unroll
    for (int ni = 0; ni < 4; ni++) b[ni] = *(const bf16x8*)&Bs[(wn * 64 + ni * 16 + l16) * 72 + ko];
#pragma unroll
    for (int mi = 0; mi < 6; mi++)
#pragma unroll
      for (int ni = 0; ni < 4; ni++)
        acc[mi][ni] = __builtin_amdgcn_mfma_f32_16x16x32_bf16(a[mi], b[ni], acc[mi][ni], 0, 0, 0);
  }
  int bb = l0g >> 12;
#pragma unroll
  for (int mi = 0; mi < 6; mi++)
#pragma unroll
    for (int r = 0; r < 4; r++) {
      int d = wm * 96 + mi * 16 + quad * 4 + r;
      float ob = out_b[d];
      float dc = fminf(fmaxf(Dp[d], -2.f), 2.f);
#pragma unroll
      for (int ni = 0; ni < 4; ni++) {
        int l = l0g + wn * 64 + ni * 16 + l16;
        float v = acc[mi][ni][r] + ob;
        if (dc != 0.f) v += dc * b2f(xln1b[(size_t)l * 192 + d]);
        sout[((size_t)bb * Dm + d) * Ln + (l & 4095)] = v;
      }
    }
}

// ---- K8: depthwise conv 3x3 + BN + residual combine -> xr (NCHW) -----------
__global__ __launch_bounds__(256) void k_conv(
    const float* __restrict__ x, const float* __restrict__ dw,
    const float* __restrict__ bn_g, const float* __restrict__ bn_b,
    const float* __restrict__ bn_rm, const float* __restrict__ bn_rv,
    const float* __restrict__ sout, const float* __restrict__ a_loc,
    const float* __restrict__ a_ssm, float* __restrict__ xr) {
  __shared__ __align__(16) float xs[64 * 64];
  int d = blockIdx.x, b = blockIdx.y, tid = threadIdx.x;
  const float* xp = x + ((size_t)b * Dm + d) * Ln;
  for (int i = tid; i < 1024; i += 256) ((float4*)xs)[i] = ((const float4*)xp)[i];
  __syncthreads();
  float w[9];
#pragma unroll
  for (int k = 0; k < 9; k++) w[k] = dw[d * 9 + k];
  float scale = bn_g[d] * rsqrtf(bn_rv[d] + 1e-5f);
  float rm = bn_rm[d], bb = bn_b[d];
  float al = a_loc[0], as_ = a_ssm[0];
  const float* sp = sout + ((size_t)b * Dm + d) * Ln;
  float* xo = xr + ((size_t)b * Dm + d) * Ln;
  for (int i = tid; i < 4096; i += 256) {
    int h = i >> 6, wc = i & 63;
    float acc = 0.f;
#pragma unroll
    for (int kh = 0; kh < 3; kh++) {
      int hh = h + kh - 1;
      if (hh < 0 || hh >= 64) continue;
#pragma unroll
      for (int kw = 0; kw < 3; kw++) {
        int ww2 = wc + kw - 1;
        if (ww2 < 0 || ww2 >= 64) continue;
        acc += xs[hh * 64 + ww2] * w[kh * 3 + kw];
      }
    }
    float xl = (acc - rm) * scale + bb;
    xo[i] = xs[i] + al * xl + as_ * sp[i];
  }
}

// ---- K9: ln2 -> bf16 xn2 [B*L, 192] row-major ------------------------------
__global__ __launch_bounds__(256) void k_ln2(
    const float* __restrict__ xr, const float* __restrict__ g, const float* __restrict__ bb,
    short* __restrict__ xn2) {
  __shared__ __align__(16) float tile[Dm * 65];
  int b = blockIdx.y, l0 = blockIdx.x * 64, tid = threadIdx.x;
  const float* xb = xr + (size_t)b * Dm * Ln;
  for (int i = tid; i < Dm * 16; i += 256) {
    int d = i >> 4, l4 = (i & 15) << 2;
    float4 v = *(const float4*)&xb[d * Ln + l0 + l4];
    tile[d * 65 + l4]     = v.x; tile[d * 65 + l4 + 1] = v.y;
    tile[d * 65 + l4 + 2] = v.z; tile[d * 65 + l4 + 3] = v.w;
  }
  __syncthreads();
  int lane = tid & 63, wv = tid >> 6;
  float g0 = g[lane], g1v = g[lane + 64], g2v = g[lane + 128];
  float b0 = bb[lane], b1v = bb[lane + 64], b2v = bb[lane + 128];
  for (int li = wv; li < 64; li += 4) {
    float v0 = tile[lane * 65 + li], v1 = tile[(lane + 64) * 65 + li], v2 = tile[(lane + 128) * 65 + li];
    float s  = wave_sum(v0 + v1 + v2);
    float sq = wave_sum(v0 * v0 + v1 * v1 + v2 * v2);
    float m = s * (1.f / 192.f);
    float inv = rsqrtf(sq * (1.f / 192.f) - m * m + 1e-5f);
    size_t base = ((size_t)b * Ln + l0 + li) * Dm;
    xn2[base + lane]       = f2b((v0 - m) * inv * g0 + b0);
    xn2[base + lane + 64]  = f2b((v1 - m) * inv * g1v + b1v);
    xn2[base + lane + 128] = f2b((v2 - m) * inv * g2v + b2v);
  }
}

// ---- K10: MFMA GEMM1: hid = gelu(xn2 @ w1^T + b1), LDS-staged coalesced out
__global__ __launch_bounds__(256) void k_gemm1(
    const short* __restrict__ xn2, const short* __restrict__ w1b,
    const float* __restrict__ b1h, short* __restrict__ hid) {
  __shared__ __align__(16) short smem[2 * 128 * 88];  // As | Bs; reused as C-stage
  short* As = smem;
  short* Bs = smem + 128 * 88;
  int m0 = blockIdx.x * 128, n0 = blockIdx.y * 128, tid = threadIdx.x;
  int lane = tid & 63, l16 = lane & 15, quad = lane >> 4;
  int wm = (tid >> 6) >> 1, wn = (tid >> 6) & 1;
  f32x4 acc[4][4] = {};
  for (int kt = 0; kt < 3; kt++) {
    int kb = kt * 64;
    for (int i = tid; i < 1024; i += 256) {
      int row = i >> 3, c8 = (i & 7) * 8;
      *(float4*)&As[row * 88 + c8] = *(const float4*)&xn2[(size_t)(m0 + row) * 192 + kb + c8];
      *(float4*)&Bs[row * 88 + c8] = *(const float4*)&w1b[(size_t)(n0 + row) * 192 + kb + c8];
    }
    __syncthreads();
#pragma unroll
    for (int ks = 0; ks < 2; ks++) {
      int ko = ks * 32 + quad * 8;
      bf16x8 a[4], b[4];
#pragma unroll
      for (int mi = 0; mi < 4; mi++) a[mi] = *(const bf16x8*)&As[(wm * 64 + mi * 16 + l16) * 88 + ko];
#pragma unroll
      for (int ni = 0; ni < 4; ni++) b[ni] = *(const bf16x8*)&Bs[(wn * 64 + ni * 16 + l16) * 88 + ko];
#pragma unroll
      for (int mi = 0; mi < 4; mi++)
#pragma unroll
        for (int ni = 0; ni < 4; ni++)
          acc[mi][ni] = __builtin_amdgcn_mfma_f32_16x16x32_bf16(a[mi], b[ni], acc[mi][ni], 0, 0, 0);
    }
    __syncthreads();
  }
  // Epilogue: bias+gelu -> bf16 C-stage in LDS [128 m][136 pad], coalesced store
  short* Cs = smem;
  float bias4[4];
#pragma unroll
  for (int ni = 0; ni < 4; ni++) bias4[ni] = b1h[n0 + wn * 64 + ni * 16 + l16];
#pragma unroll
  for (int mi = 0; mi < 4; mi++)
#pragma unroll
    for (int ni = 0; ni < 4; ni++) {
      int n = wn * 64 + ni * 16 + l16;
#pragma unroll
      for (int r = 0; r < 4; r++) {
        int m = wm * 64 + mi * 16 + quad * 4 + r;
        float v = acc[mi][ni][r] + bias4[ni];
        float g = 0.5f * v * (1.f + erff(v * 0.70710678118f));
        Cs[m * 136 + n] = f2b(g);
      }
    }
  __syncthreads();
  for (int i = tid; i < 2048; i += 256) {
    int m = i >> 4, ch = i & 15;
    *(float4*)&hid[(size_t)(m0 + m) * 768 + n0 + ch * 8] = *(const float4*)&Cs[m * 136 + ch * 8];
  }
}

// ---- K11: MFMA GEMM2 (swapped, split-d): out = xr + a*(w2 @ hid^T + b) -----
// grid (256 l-tiles, 2 d-tiles) = 512 blocks, ~4/CU by LDS.
__global__ __launch_bounds__(256) void k_gemm2(
    const short* __restrict__ hid, const short* __restrict__ w2b,
    const float* __restrict__ b2o, const float* __restrict__ xr,
    const float* __restrict__ am, float* __restrict__ out) {
  __shared__ __align__(16) short Wt[96 * 88];
  __shared__ __align__(16) short Ht[128 * 88];
  int l0g = blockIdx.x * 128, d0 = blockIdx.y * 96, tid = threadIdx.x;
  int lane = tid & 63, l16 = lane & 15, quad = lane >> 4;
  int wm = (tid >> 6) >> 1, wn = (tid >> 6) & 1;  // wm: d-half(48), wn: l-half(64)
  f32x4 acc[3][4] = {};
  for (int kt = 0; kt < 12; kt++) {
    int kb = kt * 64;
    for (int i = tid; i < 768; i += 256) {
      int row = i >> 3, c8 = (i & 7) * 8;
      *(float4*)&Wt[row * 88 + c8] = *(const float4*)&w2b[(size_t)(d0 + row) * 768 + kb + c8];
    }
    for (int i = tid; i < 1024; i += 256) {
      int row = i >> 3, c8 = (i & 7) * 8;
      *(float4*)&Ht[row * 88 + c8] = *(const float4*)&hid[(size_t)(l0g + row) * 768 + kb + c8];
    }
    __syncthreads();
#pragma unroll
    for (int ks = 0; ks < 2; ks++) {
      int ko = ks * 32 + quad * 8;
      bf16x8 a[3], b[4];
#pragma unroll
      for (int mi = 0; mi < 3; mi++) a[mi] = *(const bf16x8*)&Wt[(wm * 48 + mi * 16 + l16) * 88 + ko];
#pragma unroll
      for (int ni = 0; ni < 4; ni++) b[ni] = *(const bf16x8*)&Ht[(wn * 64 + ni * 16 + l16) * 88 + ko];
#pragma unroll
      for (int mi = 0; mi < 3; mi++)
#pragma unroll
        for (int ni = 0; ni < 4; ni++)
          acc[mi][ni] = __builtin_amdgcn_mfma_f32_16x16x32_bf16(a[mi], b[ni], acc[mi][ni], 0, 0, 0);
    }
    __syncthreads();
  }
  float alpha = am[0];
#pragma unroll
  for (int mi = 0; mi < 3; mi++)
#pragma unroll
    for (int r = 0; r < 4; r++) {
      int d = d0 + wm * 48 + mi * 16 + quad * 4 + r;
      float bias = b2o[d];
#pragma unroll
      for (int ni = 0; ni < 4; ni++) {
        int lg = l0g + wn * 64 + ni * 16 + l16;
        size_t idx = ((size_t)(lg >> 12) * Dm + d) * Ln + (lg & 4095);
        out[idx] = xr[idx] + alpha * (acc[mi][ni][r] + bias);
      }
    }
}

extern "C" void kernel_launch(void* const* d_in, const int* in_sizes, int n_in,
                              void* d_out, int out_size, void* d_ws, size_t ws_size,
                              hipStream_t stream) {
  (void)in_sizes; (void)n_in; (void)out_size; (void)ws_size;
  const float* x     = (const float*)d_in[0];
  const float* ln1_g = (const float*)d_in[1];
  const float* ln1_b = (const float*)d_in[2];
  const float* ln2_g = (const float*)d_in[3];
  const float* ln2_b = (const float*)d_in[4];
  const float* dw_w  = (const float*)d_in[5];
  const float* bn_g  = (const float*)d_in[6];
  const float* bn_b  = (const float*)d_in[7];
  const float* bn_rm = (const float*)d_in[8];
  const float* bn_rv = (const float*)d_in[9];
  const float* ssm_g = (const float*)d_in[10];
  const float* ssm_b = (const float*)d_in[11];
  const float* xp_w  = (const float*)d_in[12];
  const float* xp_b  = (const float*)d_in[13];
  const float* dt_w  = (const float*)d_in[14];
  const float* dt_b  = (const float*)d_in[15];
  const float* A_log = (const float*)d_in[16];
  const float* B_w   = (const float*)d_in[17];
  const float* C_w   = (const float*)d_in[18];
  const float* Dp    = (const float*)d_in[19];
  const float* out_w = (const float*)d_in[20];
  const float* out_b = (const float*)d_in[21];
  const float* w1    = (const float*)d_in[22];
  const float* b1    = (const float*)d_in[23];
  const float* w2    = (const float*)d_in[24];
  const float* b2    = (const float*)d_in[25];
  const float* a_loc = (const float*)d_in[26];
  const float* a_ssm = (const float*)d_in[27];
  const float* a_mlp = (const float*)d_in[28];

  float* ws = (float*)d_ws;
  short* xnb   = (short*)ws;
  short* xln1b = (short*)(ws + 3145728);
  float* abc   = ws + 6291456;
  short* yB    = (short*)(ws + 12582912);
  float* sums  = ws + 13631488;
  float* carr  = ws + 13697024;
  float* sout  = ws + 13729792;
  float* xr    = ws + 20021248;
  short* wb    = (short*)(ws + 26312704);
  short* wcatb = wb;            // [256,192]
  short* owb   = wb + 49152;    // [192,64]
  short* w1b   = wb + 61440;    // [768,192]
  short* w2b   = wb + 208896;   // [192,768]
  short* xn2   = (short*)ws;               // aliases xnb (dead after k_proj)
  short* hid   = (short*)(ws + 6291456);   // aliases abc..sout head (dead by then)
  float* out   = (float*)d_out;

  k_ln   <<<dim3(64, 8),  256, 0, stream>>>(x, ln1_g, ln1_b, ssm_g, ssm_b, xnb, xln1b);
  k_wconv<<<dim3(348),    256, 0, stream>>>(dt_w, B_w, C_w, xp_w, out_w, w1, w2, wb);
  k_proj <<<dim3(256),    256, 0, stream>>>(xnb, wcatb, dt_b, xp_b, A_log, abc);
  k_scan1<<<dim3(64, 8),   64, 0, stream>>>(abc, sums);
  k_scan2<<<dim3(8),       64, 0, stream>>>(sums, carr);
  k_scan3<<<dim3(64, 8),   64, 0, stream>>>(abc, carr, yB);
  k_out  <<<dim3(256),    256, 0, stream>>>(yB, owb, out_b, Dp, xln1b, sout);
  k_conv <<<dim3(192, 8), 256, 0, stream>>>(x, dw_w, bn_g, bn_b, bn_rm, bn_rv, sout, a_loc, a_ssm, xr);
  k_ln2  <<<dim3(64, 8),  256, 0, stream>>>(xr, ln2_g, ln2_b, xn2);
  k_gemm1<<<dim3(256, 6), 256, 0, stream>>>(xn2, w1b, b1, hid);
  k_gemm2<<<dim3(256, 2), 256, 0, stream>>>(hid, w2b, b2, xr, a_mlp, out);
}

// Round 6
// 294.832 us; speedup vs baseline: 4.1175x; 1.0476x over previous
//
#include <hip/hip_runtime.h>
#include <hip/hip_bf16.h>
#include <math.h>

// MambaBlock fused pipeline v6: residency fixes (proj/out/gemm2/scan grids).
// ws layout (floats): as v3 but sums/carr moved past wb:
//   sums @ 26490880 (131072), carr @ 26621952 (65536).

#define DEV static __device__ __forceinline__

constexpr int Bn = 8, Dm = 192, Ln = 4096, Sn = 64, Hd = 768;

typedef __attribute__((ext_vector_type(8))) short bf16x8;
typedef __attribute__((ext_vector_type(4))) float f32x4;

DEV float wave_sum(float v) {
#pragma unroll
  for (int off = 1; off < 64; off <<= 1) v += __shfl_xor(v, off);
  return v;
}

DEV short f2b(float x) {
  __hip_bfloat16 h = __float2bfloat16(x);
  return *(short*)&h;
}

DEV float b2f(short x) {
  __hip_bfloat16 h = *(__hip_bfloat16*)&x;
  return __bfloat162float(h);
}

// ---- K1: transpose + ln1 + ssm_ln -> bf16 xn, bf16 xln1 --------------------
__global__ __launch_bounds__(256) void k_ln(
    const float* __restrict__ x, const float* __restrict__ g1, const float* __restrict__ b1,
    const float* __restrict__ g2, const float* __restrict__ b2,
    short* __restrict__ xnb, short* __restrict__ xln1b) {
  __shared__ __align__(16) float tile[Dm * 65];
  int b = blockIdx.y, l0 = blockIdx.x * 64, tid = threadIdx.x;
  const float* xb = x + (size_t)b * Dm * Ln;
  for (int i = tid; i < Dm * 16; i += 256) {
    int d = i >> 4, l4 = (i & 15) << 2;
    float4 v = *(const float4*)&xb[d * Ln + l0 + l4];
    tile[d * 65 + l4]     = v.x; tile[d * 65 + l4 + 1] = v.y;
    tile[d * 65 + l4 + 2] = v.z; tile[d * 65 + l4 + 3] = v.w;
  }
  __syncthreads();
  int lane = tid & 63, wv = tid >> 6;
  float ga0 = g1[lane], ga1 = g1[lane + 64], ga2 = g1[lane + 128];
  float bb0 = b1[lane], bb1 = b1[lane + 64], bb2 = b1[lane + 128];
  float gc0 = g2[lane], gc1 = g2[lane + 64], gc2 = g2[lane + 128];
  float bc0 = b2[lane], bc1 = b2[lane + 64], bc2 = b2[lane + 128];
  for (int li = wv; li < 64; li += 4) {
    float v0 = tile[lane * 65 + li], v1 = tile[(lane + 64) * 65 + li], v2 = tile[(lane + 128) * 65 + li];
    float s  = wave_sum(v0 + v1 + v2);
    float sq = wave_sum(v0 * v0 + v1 * v1 + v2 * v2);
    float m = s * (1.f / 192.f);
    float inv = rsqrtf(sq * (1.f / 192.f) - m * m + 1e-5f);
    float y0 = (v0 - m) * inv * ga0 + bb0;
    float y1 = (v1 - m) * inv * ga1 + bb1;
    float y2 = (v2 - m) * inv * ga2 + bb2;
    float s2  = wave_sum(y0 + y1 + y2);
    float sq2 = wave_sum(y0 * y0 + y1 * y1 + y2 * y2);
    float m2 = s2 * (1.f / 192.f);
    float inv2 = rsqrtf(sq2 * (1.f / 192.f) - m2 * m2 + 1e-5f);
    size_t base = ((size_t)b * Ln + l0 + li) * Dm;
    xln1b[base + lane]       = f2b(y0);
    xln1b[base + lane + 64]  = f2b(y1);
    xln1b[base + lane + 128] = f2b(y2);
    xnb[base + lane]       = f2b((y0 - m2) * inv2 * gc0 + bc0);
    xnb[base + lane + 64]  = f2b((y1 - m2) * inv2 * gc1 + bc1);
    xnb[base + lane + 128] = f2b((y2 - m2) * inv2 * gc2 + bc2);
  }
}

// ---- K2: weights -> bf16 (dt|B|C|xp cat, out_w, w1, w2) --------------------
__global__ __launch_bounds__(256) void k_wconv(
    const float* __restrict__ dt_w, const float* __restrict__ B_w,
    const float* __restrict__ C_w, const float* __restrict__ xp_w,
    const float* __restrict__ out_w, const float* __restrict__ w1,
    const float* __restrict__ w2, short* __restrict__ wb) {
  int i = blockIdx.x * 256 + threadIdx.x;  // 89088 float4 groups total
  const float4* src;
  if (i < 3072)       src = (const float4*)dt_w + i;
  else if (i < 6144)  src = (const float4*)B_w + (i - 3072);
  else if (i < 9216)  src = (const float4*)C_w + (i - 6144);
  else if (i < 12288) src = (const float4*)xp_w + (i - 9216);
  else if (i < 15360) src = (const float4*)out_w + (i - 12288);
  else if (i < 52224) src = (const float4*)w1 + (i - 15360);
  else                src = (const float4*)w2 + (i - 52224);
  float4 v = *src;
  int o = i * 4;
  wb[o]     = f2b(v.x); wb[o + 1] = f2b(v.y);
  wb[o + 2] = f2b(v.z); wb[o + 3] = f2b(v.w);
}

// ---- K3: MFMA proj GEMM [32768x256, K=192] + in-register SSM epilogue ------
// m-tile 64 (grid 512 = 2 blocks/CU). Wave w: rows w*16..w*16+15, all 256 n.
__global__ __launch_bounds__(256) void k_proj(
    const short* __restrict__ xnb, const short* __restrict__ wcat,
    const float* __restrict__ dt_b, const float* __restrict__ xp_b,
    const float* __restrict__ A_log, float* __restrict__ abc) {
  __shared__ __align__(16) short As[64 * 72];
  __shared__ __align__(16) short Bs[256 * 72];
  int m0 = blockIdx.x * 64, tid = threadIdx.x;
  int lane = tid & 63, l16 = lane & 15, quad = lane >> 4, w = tid >> 6;
  f32x4 acc[16] = {};
  for (int kt = 0; kt < 3; kt++) {
    int kb = kt * 64;
    for (int i = tid; i < 512; i += 256) {
      int row = i >> 3, c8 = (i & 7) * 8;
      *(float4*)&As[row * 72 + c8] = *(const float4*)&xnb[(size_t)(m0 + row) * 192 + kb + c8];
    }
    for (int i = tid; i < 2048; i += 256) {
      int row = i >> 3, c8 = (i & 7) * 8;
      *(float4*)&Bs[row * 72 + c8] = *(const float4*)&wcat[(size_t)row * 192 + kb + c8];
    }
    __syncthreads();
#pragma unroll
    for (int ks = 0; ks < 2; ks++) {
      int ko = ks * 32 + quad * 8;
      bf16x8 a0 = *(const bf16x8*)&As[(w * 16 + l16) * 72 + ko];
#pragma unroll
      for (int nh = 0; nh < 2; nh++) {
        bf16x8 bfr[8];
#pragma unroll
        for (int j = 0; j < 8; j++) bfr[j] = *(const bf16x8*)&Bs[((nh * 8 + j) * 16 + l16) * 72 + ko];
#pragma unroll
        for (int j = 0; j < 8; j++)
          acc[nh * 8 + j] = __builtin_amdgcn_mfma_f32_16x16x32_bf16(a0, bfr[j], acc[nh * 8 + j], 0, 0, 0);
      }
    }
    __syncthreads();
  }
  float Av[4], dtb[4], xpb[4];
#pragma unroll
  for (int ni = 0; ni < 4; ni++) {
    int s = ni * 16 + l16;
    Av[ni] = -expf(A_log[s]); dtb[ni] = dt_b[s]; xpb[ni] = xp_b[s];
  }
#pragma unroll
  for (int r = 0; r < 4; r++) {
    int m = m0 + w * 16 + quad * 4 + r;
    float* orow = abc + (size_t)m * 192;
#pragma unroll
    for (int ni = 0; ni < 4; ni++) {
      int s = ni * 16 + l16;
      float z = acc[ni][r] + dtb[ni];
      float sp = (z > 20.f) ? z : log1pf(expf(z));
      float delta = sp * 0.01f + 0.0001f;
      float bt  = acc[ni + 4][r];
      float ct  = acc[ni + 8][r];
      float xpv = acc[ni + 12][r] + xpb[ni];
      float dA = fminf(fmaxf(delta * Av[ni], -10.f), -0.0001f);
      float Ae = fminf(fmaxf(expf(dA), 0.001f), 0.999f) + 1e-10f;
      orow[s]       = Ae;
      orow[64 + s]  = delta * bt * xpv;
      orow[128 + s] = ct;
    }
  }
}

// ---- K4: scan phase 1 (32-step chunk summaries) ----------------------------
__global__ __launch_bounds__(64) void k_scan1(const float* __restrict__ abc, float* __restrict__ sums) {
  int c = blockIdx.x, b = blockIdx.y, s = threadIdx.x;
  const float* p = abc + ((size_t)b * Ln + c * 32) * 192;
  float prodA = 1.f, h = 0.f;
  int t = 0;
  if (c == 0) { prodA = p[s]; h = p[64 + s]; t = 1; }
#pragma unroll 4
  for (; t < 32; t++) {
    float a = p[t * 192 + s], bx = p[t * 192 + 64 + s];
    h = a * (h + bx);
    prodA *= a;
  }
  int ci = b * 128 + c;
  sums[(ci * 2 + 0) * 64 + s] = prodA;
  sums[(ci * 2 + 1) * 64 + s] = h;
}

// ---- K5: scan phase 2 (carry chain over 128 chunks), one block per batch ---
__global__ __launch_bounds__(64) void k_scan2(const float* __restrict__ sums, float* __restrict__ carries) {
  int b = blockIdx.x, s = threadIdx.x;
  float cur = 0.f;
#pragma unroll 4
  for (int c = 0; c < 128; c++) {
    int ci = b * 128 + c;
    carries[ci * 64 + s] = cur;
    cur = sums[(ci * 2 + 0) * 64 + s] * cur + sums[(ci * 2 + 1) * 64 + s];
  }
}

// ---- K6: scan phase 3 (replay, y = C*h -> bf16) ----------------------------
__global__ __launch_bounds__(64) void k_scan3(const float* __restrict__ abc, const float* __restrict__ carries,
                                              short* __restrict__ y) {
  int c = blockIdx.x, b = blockIdx.y, s = threadIdx.x;
  size_t r0 = (size_t)b * Ln + c * 32;
  const float* p = abc + r0 * 192;
  short* yo = y + r0 * 64;
  float h = carries[(b * 128 + c) * 64 + s];
  int t = 0;
  if (c == 0) { h = p[64 + s]; yo[s] = f2b(p[128 + s] * h); t = 1; }
#pragma unroll 4
  for (; t < 32; t++) {
    float a = p[t * 192 + s], bx = p[t * 192 + 64 + s], ct = p[t * 192 + 128 + s];
    h = a * (h + bx);
    yo[t * 64 + s] = f2b(ct * h);
  }
}

// ---- K7: MFMA out-proj (swapped, split-d): sout[d][l] = out_w @ y^T + b ----
// grid (512 l-tiles of 64, 2 d-halves of 96) = 1024 blocks, 4/CU.
__global__ __launch_bounds__(256) void k_out(
    const short* __restrict__ y, const short* __restrict__ owb, const float* __restrict__ out_b,
    const float* __restrict__ Dp, const short* __restrict__ xln1b, float* __restrict__ sout) {
  __shared__ __align__(16) short As[96 * 72];
  __shared__ __align__(16) short Bs[64 * 72];
  int l0g = blockIdx.x * 64, d0 = blockIdx.y * 96, tid = threadIdx.x;
  int lane = tid & 63, l16 = lane & 15, quad = lane >> 4;
  int wm = (tid >> 6) >> 1, wn = (tid >> 6) & 1;  // wm: d-half(48), wn: l-half(32)
  f32x4 acc[3][2] = {};
  for (int i = tid; i < 768; i += 256) {
    int row = i >> 3, c8 = (i & 7) * 8;
    *(float4*)&As[row * 72 + c8] = *(const float4*)&owb[(d0 + row) * 64 + c8];
  }
  for (int i = tid; i < 512; i += 256) {
    int row = i >> 3, c8 = (i & 7) * 8;
    *(float4*)&Bs[row * 72 + c8] = *(const float4*)&y[(size_t)(l0g + row) * 64 + c8];
  }
  __syncthreads();
#pragma unroll
  for (int ks = 0; ks < 2; ks++) {
    int ko = ks * 32 + quad * 8;
    bf16x8 a[3], b[2];
#pragma unroll
    for (int mi = 0; mi < 3; mi++) a[mi] = *(const bf16x8*)&As[(wm * 48 + mi * 16 + l16) * 72 + ko];
#pragma unroll
    for (int ni = 0; ni < 2; ni++) b[ni] = *(const bf16x8*)&Bs[(wn * 32 + ni * 16 + l16) * 72 + ko];
#pragma unroll
    for (int mi = 0; mi < 3; mi++)
#pragma unroll
      for (int ni = 0; ni < 2; ni++)
        acc[mi][ni] = __builtin_amdgcn_mfma_f32_16x16x32_bf16(a[mi], b[ni], acc[mi][ni], 0, 0, 0);
  }
  int bb = l0g >> 12;
#pragma unroll
  for (int mi = 0; mi < 3; mi++)
#pragma unroll
    for (int r = 0; r < 4; r++) {
      int d = d0 + wm * 48 + mi * 16 + quad * 4 + r;
      float ob = out_b[d];
      float dc = fminf(fmaxf(Dp[d], -2.f), 2.f);
#pragma unroll
      for (int ni = 0; ni < 2; ni++) {
        int l = l0g + wn * 32 + ni * 16 + l16;
        float v = acc[mi][ni][r] + ob;
        if (dc != 0.f) v += dc * b2f(xln1b[(size_t)l * 192 + d]);
        sout[((size_t)bb * Dm + d) * Ln + (l & 4095)] = v;
      }
    }
}

// ---- K8: depthwise conv 3x3 + BN + residual combine -> xr (NCHW) -----------
__global__ __launch_bounds__(256) void k_conv(
    const float* __restrict__ x, const float* __restrict__ dw,
    const float* __restrict__ bn_g, const float* __restrict__ bn_b,
    const float* __restrict__ bn_rm, const float* __restrict__ bn_rv,
    const float* __restrict__ sout, const float* __restrict__ a_loc,
    const float* __restrict__ a_ssm, float* __restrict__ xr) {
  __shared__ __align__(16) float xs[64 * 64];
  int d = blockIdx.x, b = blockIdx.y, tid = threadIdx.x;
  const float* xp = x + ((size_t)b * Dm + d) * Ln;
  for (int i = tid; i < 1024; i += 256) ((float4*)xs)[i] = ((const float4*)xp)[i];
  __syncthreads();
  float w[9];
#pragma unroll
  for (int k = 0; k < 9; k++) w[k] = dw[d * 9 + k];
  float scale = bn_g[d] * rsqrtf(bn_rv[d] + 1e-5f);
  float rm = bn_rm[d], bb = bn_b[d];
  float al = a_loc[0], as_ = a_ssm[0];
  const float* sp = sout + ((size_t)b * Dm + d) * Ln;
  float* xo = xr + ((size_t)b * Dm + d) * Ln;
  for (int i = tid; i < 4096; i += 256) {
    int h = i >> 6, wc = i & 63;
    float acc = 0.f;
#pragma unroll
    for (int kh = 0; kh < 3; kh++) {
      int hh = h + kh - 1;
      if (hh < 0 || hh >= 64) continue;
#pragma unroll
      for (int kw = 0; kw < 3; kw++) {
        int ww2 = wc + kw - 1;
        if (ww2 < 0 || ww2 >= 64) continue;
        acc += xs[hh * 64 + ww2] * w[kh * 3 + kw];
      }
    }
    float xl = (acc - rm) * scale + bb;
    xo[i] = xs[i] + al * xl + as_ * sp[i];
  }
}

// ---- K9: ln2 -> bf16 xn2 [B*L, 192] row-major ------------------------------
__global__ __launch_bounds__(256) void k_ln2(
    const float* __restrict__ xr, const float* __restrict__ g, const float* __restrict__ bb,
    short* __restrict__ xn2) {
  __shared__ __align__(16) float tile[Dm * 65];
  int b = blockIdx.y, l0 = blockIdx.x * 64, tid = threadIdx.x;
  const float* xb = xr + (size_t)b * Dm * Ln;
  for (int i = tid; i < Dm * 16; i += 256) {
    int d = i >> 4, l4 = (i & 15) << 2;
    float4 v = *(const float4*)&xb[d * Ln + l0 + l4];
    tile[d * 65 + l4]     = v.x; tile[d * 65 + l4 + 1] = v.y;
    tile[d * 65 + l4 + 2] = v.z; tile[d * 65 + l4 + 3] = v.w;
  }
  __syncthreads();
  int lane = tid & 63, wv = tid >> 6;
  float g0 = g[lane], g1v = g[lane + 64], g2v = g[lane + 128];
  float b0 = bb[lane], b1v = bb[lane + 64], b2v = bb[lane + 128];
  for (int li = wv; li < 64; li += 4) {
    float v0 = tile[lane * 65 + li], v1 = tile[(lane + 64) * 65 + li], v2 = tile[(lane + 128) * 65 + li];
    float s  = wave_sum(v0 + v1 + v2);
    float sq = wave_sum(v0 * v0 + v1 * v1 + v2 * v2);
    float m = s * (1.f / 192.f);
    float inv = rsqrtf(sq * (1.f / 192.f) - m * m + 1e-5f);
    size_t base = ((size_t)b * Ln + l0 + li) * Dm;
    xn2[base + lane]       = f2b((v0 - m) * inv * g0 + b0);
    xn2[base + lane + 64]  = f2b((v1 - m) * inv * g1v + b1v);
    xn2[base + lane + 128] = f2b((v2 - m) * inv * g2v + b2v);
  }
}

// ---- K10: MFMA GEMM1: hid = gelu(xn2 @ w1^T + b1), LDS-staged coalesced out
__global__ __launch_bounds__(256) void k_gemm1(
    const short* __restrict__ xn2, const short* __restrict__ w1b,
    const float* __restrict__ b1h, short* __restrict__ hid) {
  __shared__ __align__(16) short smem[2 * 128 * 88];  // As | Bs; reused as C-stage
  short* As = smem;
  short* Bs = smem + 128 * 88;
  int m0 = blockIdx.x * 128, n0 = blockIdx.y * 128, tid = threadIdx.x;
  int lane = tid & 63, l16 = lane & 15, quad = lane >> 4;
  int wm = (tid >> 6) >> 1, wn = (tid >> 6) & 1;
  f32x4 acc[4][4] = {};
  for (int kt = 0; kt < 3; kt++) {
    int kb = kt * 64;
    for (int i = tid; i < 1024; i += 256) {
      int row = i >> 3, c8 = (i & 7) * 8;
      *(float4*)&As[row * 88 + c8] = *(const float4*)&xn2[(size_t)(m0 + row) * 192 + kb + c8];
      *(float4*)&Bs[row * 88 + c8] = *(const float4*)&w1b[(size_t)(n0 + row) * 192 + kb + c8];
    }
    __syncthreads();
#pragma unroll
    for (int ks = 0; ks < 2; ks++) {
      int ko = ks * 32 + quad * 8;
      bf16x8 a[4], b[4];
#pragma unroll
      for (int mi = 0; mi < 4; mi++) a[mi] = *(const bf16x8*)&As[(wm * 64 + mi * 16 + l16) * 88 + ko];
#pragma unroll
      for (int ni = 0; ni < 4; ni++) b[ni] = *(const bf16x8*)&Bs[(wn * 64 + ni * 16 + l16) * 88 + ko];
#pragma unroll
      for (int mi = 0; mi < 4; mi++)
#pragma unroll
        for (int ni = 0; ni < 4; ni++)
          acc[mi][ni] = __builtin_amdgcn_mfma_f32_16x16x32_bf16(a[mi], b[ni], acc[mi][ni], 0, 0, 0);
    }
    __syncthreads();
  }
  short* Cs = smem;
  float bias4[4];
#pragma unroll
  for (int ni = 0; ni < 4; ni++) bias4[ni] = b1h[n0 + wn * 64 + ni * 16 + l16];
#pragma unroll
  for (int mi = 0; mi < 4; mi++)
#pragma unroll
    for (int ni = 0; ni < 4; ni++) {
      int n = wn * 64 + ni * 16 + l16;
#pragma unroll
      for (int r = 0; r < 4; r++) {
        int m = wm * 64 + mi * 16 + quad * 4 + r;
        float v = acc[mi][ni][r] + bias4[ni];
        float g = 0.5f * v * (1.f + erff(v * 0.70710678118f));
        Cs[m * 136 + n] = f2b(g);
      }
    }
  __syncthreads();
  for (int i = tid; i < 2048; i += 256) {
    int m = i >> 4, ch = i & 15;
    *(float4*)&hid[(size_t)(m0 + m) * 768 + n0 + ch * 8] = *(const float4*)&Cs[m * 136 + ch * 8];
  }
}

// ---- K11: MFMA GEMM2 (swapped, split-d): out = xr + a*(w2 @ hid^T + b) -----
// grid (512 l-tiles of 64, 2 d-tiles of 96) = 1024 blocks, 4/CU.
__global__ __launch_bounds__(256) void k_gemm2(
    const short* __restrict__ hid, const short* __restrict__ w2b,
    const float* __restrict__ b2o, const float* __restrict__ xr,
    const float* __restrict__ am, float* __restrict__ out) {
  __shared__ __align__(16) short Wt[96 * 88];
  __shared__ __align__(16) short Ht[64 * 88];
  int l0g = blockIdx.x * 64, d0 = blockIdx.y * 96, tid = threadIdx.x;
  int lane = tid & 63, l16 = lane & 15, quad = lane >> 4;
  int wm = (tid >> 6) >> 1, wn = (tid >> 6) & 1;  // wm: d-half(48), wn: l-half(32)
  f32x4 acc[3][2] = {};
  for (int kt = 0; kt < 12; kt++) {
    int kb = kt * 64;
    for (int i = tid; i < 768; i += 256) {
      int row = i >> 3, c8 = (i & 7) * 8;
      *(float4*)&Wt[row * 88 + c8] = *(const float4*)&w2b[(size_t)(d0 + row) * 768 + kb + c8];
    }
    for (int i = tid; i < 512; i += 256) {
      int row = i >> 3, c8 = (i & 7) * 8;
      *(float4*)&Ht[row * 88 + c8] = *(const float4*)&hid[(size_t)(l0g + row) * 768 + kb + c8];
    }
    __syncthreads();
#pragma unroll
    for (int ks = 0; ks < 2; ks++) {
      int ko = ks * 32 + quad * 8;
      bf16x8 a[3], b[2];
#pragma unroll
      for (int mi = 0; mi < 3; mi++) a[mi] = *(const bf16x8*)&Wt[(wm * 48 + mi * 16 + l16) * 88 + ko];
#pragma unroll
      for (int ni = 0; ni < 2; ni++) b[ni] = *(const bf16x8*)&Ht[(wn * 32 + ni * 16 + l16) * 88 + ko];
#pragma unroll
      for (int mi = 0; mi < 3; mi++)
#pragma unroll
        for (int ni = 0; ni < 2; ni++)
          acc[mi][ni] = __builtin_amdgcn_mfma_f32_16x16x32_bf16(a[mi], b[ni], acc[mi][ni], 0, 0, 0);
    }
    __syncthreads();
  }
  float alpha = am[0];
#pragma unroll
  for (int mi = 0; mi < 3; mi++)
#pragma unroll
    for (int r = 0; r < 4; r++) {
      int d = d0 + wm * 48 + mi * 16 + quad * 4 + r;
      float bias = b2o[d];
#pragma unroll
      for (int ni = 0; ni < 2; ni++) {
        int lg = l0g + wn * 32 + ni * 16 + l16;
        size_t idx = ((size_t)(lg >> 12) * Dm + d) * Ln + (lg & 4095);
        out[idx] = xr[idx] + alpha * (acc[mi][ni][r] + bias);
      }
    }
}

extern "C" void kernel_launch(void* const* d_in, const int* in_sizes, int n_in,
                              void* d_out, int out_size, void* d_ws, size_t ws_size,
                              hipStream_t stream) {
  (void)in_sizes; (void)n_in; (void)out_size; (void)ws_size;
  const float* x     = (const float*)d_in[0];
  const float* ln1_g = (const float*)d_in[1];
  const float* ln1_b = (const float*)d_in[2];
  const float* ln2_g = (const float*)d_in[3];
  const float* ln2_b = (const float*)d_in[4];
  const float* dw_w  = (const float*)d_in[5];
  const float* bn_g  = (const float*)d_in[6];
  const float* bn_b  = (const float*)d_in[7];
  const float* bn_rm = (const float*)d_in[8];
  const float* bn_rv = (const float*)d_in[9];
  const float* ssm_g = (const float*)d_in[10];
  const float* ssm_b = (const float*)d_in[11];
  const float* xp_w  = (const float*)d_in[12];
  const float* xp_b  = (const float*)d_in[13];
  const float* dt_w  = (const float*)d_in[14];
  const float* dt_b  = (const float*)d_in[15];
  const float* A_log = (const float*)d_in[16];
  const float* B_w   = (const float*)d_in[17];
  const float* C_w   = (const float*)d_in[18];
  const float* Dp    = (const float*)d_in[19];
  const float* out_w = (const float*)d_in[20];
  const float* out_b = (const float*)d_in[21];
  const float* w1    = (const float*)d_in[22];
  const float* b1    = (const float*)d_in[23];
  const float* w2    = (const float*)d_in[24];
  const float* b2    = (const float*)d_in[25];
  const float* a_loc = (const float*)d_in[26];
  const float* a_ssm = (const float*)d_in[27];
  const float* a_mlp = (const float*)d_in[28];

  float* ws = (float*)d_ws;
  short* xnb   = (short*)ws;
  short* xln1b = (short*)(ws + 3145728);
  float* abc   = ws + 6291456;
  short* yB    = (short*)(ws + 12582912);
  float* sout  = ws + 13729792;
  float* xr    = ws + 20021248;
  short* wb    = (short*)(ws + 26312704);
  float* sums  = ws + 26490880;   // 131072 floats
  float* carr  = ws + 26621952;   // 65536 floats
  short* wcatb = wb;            // [256,192]
  short* owb   = wb + 49152;    // [192,64]
  short* w1b   = wb + 61440;    // [768,192]
  short* w2b   = wb + 208896;   // [192,768]
  short* xn2   = (short*)ws;               // aliases xnb (dead after k_proj)
  short* hid   = (short*)(ws + 6291456);   // aliases abc..sout head (dead by then)
  float* out   = (float*)d_out;

  k_ln   <<<dim3(64, 8),  256, 0, stream>>>(x, ln1_g, ln1_b, ssm_g, ssm_b, xnb, xln1b);
  k_wconv<<<dim3(348),    256, 0, stream>>>(dt_w, B_w, C_w, xp_w, out_w, w1, w2, wb);
  k_proj <<<dim3(512),    256, 0, stream>>>(xnb, wcatb, dt_b, xp_b, A_log, abc);
  k_scan1<<<dim3(128, 8),  64, 0, stream>>>(abc, sums);
  k_scan2<<<dim3(8),       64, 0, stream>>>(sums, carr);
  k_scan3<<<dim3(128, 8),  64, 0, stream>>>(abc, carr, yB);
  k_out  <<<dim3(512, 2), 256, 0, stream>>>(yB, owb, out_b, Dp, xln1b, sout);
  k_conv <<<dim3(192, 8), 256, 0, stream>>>(x, dw_w, bn_g, bn_b, bn_rm, bn_rv, sout, a_loc, a_ssm, xr);
  k_ln2  <<<dim3(64, 8),  256, 0, stream>>>(xr, ln2_g, ln2_b, xn2);
  k_gemm1<<<dim3(256, 6), 256, 0, stream>>>(xn2, w1b, b1, hid);
  k_gemm2<<<dim3(512, 2), 256, 0, stream>>>(hid, w2b, b2, xr, a_mlp, out);
}